// Round 2
// baseline (973.556 us; speedup 1.0000x reference)
//
#include <hip/hip_runtime.h>
#include <math.h>

#define NN 50000        // nodes
#define NE 800000       // edges
#define DIN 256
#define DOUT 768
#define NPAD 50176      // NN padded to multiple of 128 for GEMM tile staging

typedef _Float16 half8 __attribute__((ext_vector_type(8)));
typedef _Float16 half4 __attribute__((ext_vector_type(4)));
typedef float    f32x4 __attribute__((ext_vector_type(4)));

// ---------------------------------------------------------------------------
// Degree / CSR construction
// ---------------------------------------------------------------------------
__global__ void init_deg_cnt(float* __restrict__ deg, int* __restrict__ cnt) {
    int i = blockIdx.x * 256 + threadIdx.x;
    if (i < NN) { deg[i] = 1.0f; cnt[i] = 0; }   // self-loop weight 1 pre-added
}

__global__ void edge_deg_cnt(const int* __restrict__ ei, const float* __restrict__ ea,
                             float* __restrict__ deg, int* __restrict__ cnt) {
    int e = blockIdx.x * 256 + threadIdx.x;
    if (e >= NE) return;
    int dst = ei[NE + e];
    atomicAdd(&deg[dst], ea[e]);
    atomicAdd(&cnt[dst], 1);
}

__global__ void compute_dinv(const float* __restrict__ deg, float* __restrict__ dinv) {
    int i = blockIdx.x * 256 + threadIdx.x;
    if (i < NN) { float d = deg[i]; dinv[i] = d > 0.f ? rsqrtf(d) : 0.f; }
}

// 1024-thread single-block scan of cnt -> row_ptr (+ cursor copy)
__global__ __launch_bounds__(1024) void scan_kernel(
        const int* __restrict__ cnt, int* __restrict__ row_ptr,
        int* __restrict__ cursor) {
    __shared__ int ssum[1024];
    int t = threadIdx.x;
    const int chunk = (NN + 1023) / 1024;   // 49
    int beg = t * chunk;
    int end = beg + chunk; if (end > NN) end = NN;
    int s = 0;
    for (int i = beg; i < end; ++i) s += cnt[i];
    ssum[t] = s;
    __syncthreads();
    if (t == 0) {
        int run = 0;
        for (int i = 0; i < 1024; ++i) { int v = ssum[i]; ssum[i] = run; run += v; }
    }
    __syncthreads();
    int run = ssum[t];
    for (int i = beg; i < end; ++i) {
        row_ptr[i] = run; cursor[i] = run; run += cnt[i];
    }
    if (t == 0) row_ptr[NN] = NE;
}

__global__ void edge_scatter(const int* __restrict__ ei, const float* __restrict__ ea,
                             const float* __restrict__ dinv, int* __restrict__ cursor,
                             int* __restrict__ col, float* __restrict__ val) {
    int e = blockIdx.x * 256 + threadIdx.x;
    if (e >= NE) return;
    int s = ei[e];
    int d = ei[NE + e];
    int pos = atomicAdd(&cursor[d], 1);
    col[pos] = s;
    val[pos] = dinv[s] * ea[e] * dinv[d];
}

// convert x fp32 -> fp16 (4 elems/thread)
__global__ void x2h_kernel(const float* __restrict__ x, _Float16* __restrict__ Xh) {
    int i = blockIdx.x * 256 + threadIdx.x;
    if (i >= NN * DIN / 4) return;
    float4 v = ((const float4*)x)[i];
    half4 h; h[0] = (_Float16)v.x; h[1] = (_Float16)v.y;
    h[2] = (_Float16)v.z; h[3] = (_Float16)v.w;
    ((half4*)Xh)[i] = h;
}

__device__ inline float rv(const float* __restrict__ R, int c) {
    return R ? R[c] : 1.f;
}

// ---------------------------------------------------------------------------
// Aggregation, fp16 in / fp16 out, fp32 accumulate. One WAVE per node.
// Row = 256 fp16 = 512 B = 64 lanes x 8 B (full-wave gather, one row per
// vector instruction). 8-edge unroll => 8 gathers in flight per wave to
// hide the colv->gather dependent latency chain (L2 ~200cy + L3 ~500cy).
// col/val/R reads are wave-uniform -> broadcast from one cache line.
// ---------------------------------------------------------------------------
__global__ __launch_bounds__(256) void agg_kernel(
        const _Float16* __restrict__ Gin, int sIn,
        _Float16* __restrict__ Gout, int sOut,
        const float* __restrict__ Rin, float* __restrict__ Rout,
        const int* __restrict__ rowp, const int* __restrict__ colv,
        const float* __restrict__ val, const float* __restrict__ dinv) {
    int node = blockIdx.x * 4 + (threadIdx.x >> 6);
    if (node >= NN) return;
    int lane = threadIdx.x & 63;
    const _Float16* gb = Gin + lane * 4;
    float acc[4] = {0.f, 0.f, 0.f, 0.f};
    float racc = 0.f;
    int beg = rowp[node], end = rowp[node + 1];
    int k = beg;
    for (; k + 8 <= end; k += 8) {
        int   c0 = colv[k+0], c1 = colv[k+1], c2 = colv[k+2], c3 = colv[k+3];
        int   c4 = colv[k+4], c5 = colv[k+5], c6 = colv[k+6], c7 = colv[k+7];
        float v0 = val[k+0], v1 = val[k+1], v2 = val[k+2], v3 = val[k+3];
        float v4 = val[k+4], v5 = val[k+5], v6 = val[k+6], v7 = val[k+7];
        half4 g0 = *(const half4*)(gb + (size_t)c0 * sIn);
        half4 g1 = *(const half4*)(gb + (size_t)c1 * sIn);
        half4 g2 = *(const half4*)(gb + (size_t)c2 * sIn);
        half4 g3 = *(const half4*)(gb + (size_t)c3 * sIn);
        half4 g4 = *(const half4*)(gb + (size_t)c4 * sIn);
        half4 g5 = *(const half4*)(gb + (size_t)c5 * sIn);
        half4 g6 = *(const half4*)(gb + (size_t)c6 * sIn);
        half4 g7 = *(const half4*)(gb + (size_t)c7 * sIn);
#pragma unroll
        for (int j = 0; j < 4; ++j)
            acc[j] += v0 * (float)g0[j] + v1 * (float)g1[j]
                    + v2 * (float)g2[j] + v3 * (float)g3[j]
                    + v4 * (float)g4[j] + v5 * (float)g5[j]
                    + v6 * (float)g6[j] + v7 * (float)g7[j];
        if (Rout)
            racc += v0 * rv(Rin, c0) + v1 * rv(Rin, c1)
                  + v2 * rv(Rin, c2) + v3 * rv(Rin, c3)
                  + v4 * rv(Rin, c4) + v5 * rv(Rin, c5)
                  + v6 * rv(Rin, c6) + v7 * rv(Rin, c7);
    }
    for (; k + 4 <= end; k += 4) {
        int   c0 = colv[k+0], c1 = colv[k+1], c2 = colv[k+2], c3 = colv[k+3];
        float v0 = val[k+0], v1 = val[k+1], v2 = val[k+2], v3 = val[k+3];
        half4 g0 = *(const half4*)(gb + (size_t)c0 * sIn);
        half4 g1 = *(const half4*)(gb + (size_t)c1 * sIn);
        half4 g2 = *(const half4*)(gb + (size_t)c2 * sIn);
        half4 g3 = *(const half4*)(gb + (size_t)c3 * sIn);
#pragma unroll
        for (int j = 0; j < 4; ++j)
            acc[j] += v0 * (float)g0[j] + v1 * (float)g1[j]
                    + v2 * (float)g2[j] + v3 * (float)g3[j];
        if (Rout)
            racc += v0 * rv(Rin, c0) + v1 * rv(Rin, c1)
                  + v2 * rv(Rin, c2) + v3 * rv(Rin, c3);
    }
    for (; k < end; ++k) {
        int c = colv[k]; float v = val[k];
        half4 g = *(const half4*)(gb + (size_t)c * sIn);
#pragma unroll
        for (int j = 0; j < 4; ++j) acc[j] += v * (float)g[j];
        if (Rout) racc += v * rv(Rin, c);
    }
    float dv = dinv[node], sv = dv * dv;
    half4 gs = *(const half4*)(gb + (size_t)node * sIn);
#pragma unroll
    for (int j = 0; j < 4; ++j) acc[j] += sv * (float)gs[j];
    half4 o;
#pragma unroll
    for (int j = 0; j < 4; ++j) o[j] = (_Float16)acc[j];
    *(half4*)(Gout + (size_t)node * sOut + lane * 4) = o;
    if (Rout && lane == 0)
        Rout[node] = racc + sv * (Rin ? Rin[node] : 1.f);
}

// ---------------------------------------------------------------------------
// Weight-side precompute, consolidated into 4 launches.
// ---------------------------------------------------------------------------
__global__ __launch_bounds__(256) void wp1(
        const float* __restrict__ W2, const float* __restrict__ W3,
        const float* __restrict__ b2, const float* __restrict__ b3,
        float* __restrict__ W2sq, float* __restrict__ W3_2,
        float* __restrict__ bw2, float* __restrict__ bw3a) {
    int b = blockIdx.x, j = threadIdx.x;
    const float* A; const float* B; float* C;
    if (b < 256)      { A = W2 + b * 256;         B = W2; C = W2sq + b * 256; }
    else if (b < 512) { A = W3 + (b - 256) * 256; B = W3; C = W3_2 + (b - 256) * 256; }
    else if (b == 512){ A = b2;                   B = W2; C = bw2; }
    else              { A = b3;                   B = W3; C = bw3a; }
    float s = 0.f;
#pragma unroll 8
    for (int k = 0; k < 256; ++k) s += A[k] * B[k * 256 + j];
    C[j] = s;
}

__global__ __launch_bounds__(256) void wp2(
        const float* __restrict__ W3_2, const float* __restrict__ W3,
        const float* __restrict__ bw3a,
        float* __restrict__ W3_4, float* __restrict__ bw3b) {
    int b = blockIdx.x, j = threadIdx.x;
    const float* A; const float* B; float* C;
    if (b < 256) { A = W3_2 + b * 256; B = W3_2; C = W3_4 + b * 256; }
    else         { A = bw3a;           B = W3;   C = bw3b; }
    float s = 0.f;
#pragma unroll 8
    for (int k = 0; k < 256; ++k) s += A[k] * B[k * 256 + j];
    C[j] = s;
}

__global__ __launch_bounds__(256) void wp3(
        const float* __restrict__ W1, const float* __restrict__ W2sq,
        const float* __restrict__ W3_4, const float* __restrict__ Wp,
        const float* __restrict__ W3, const float* __restrict__ bw3b,
        _Float16* __restrict__ Mt, float* __restrict__ bw3c) {
    int b = blockIdx.x, j = threadIdx.x;
    if (b == 768) {   // bw3c = bw3b @ W3
        float s = 0.f;
#pragma unroll 8
        for (int k = 0; k < 256; ++k) s += bw3b[k] * W3[k * 256 + j];
        bw3c[j] = s;
        return;
    }
    int kk = b;                       // output row of Mcat = column of Mt
    int blk = kk >> 8;                // 0,1,2
    const float* A = (blk == 0) ? (W1 + kk * 256)
                   : (blk == 1) ? (W2sq + (kk - 256) * 256)
                                : (W3_4 + (kk - 512) * 256);
    const float* B = Wp + (size_t)(blk * 256) * 768;
    float s0 = 0.f, s1 = 0.f, s2 = 0.f;
#pragma unroll 4
    for (int m = 0; m < 256; ++m) {
        float a = A[m];
        const float* br = B + (size_t)m * 768;
        s0 += a * br[j]; s1 += a * br[j + 256]; s2 += a * br[j + 512];
    }
    // Mt[n][k] = Mcat[k][n]
    Mt[(size_t)j * 768 + kk]         = (_Float16)s0;
    Mt[(size_t)(j + 256) * 768 + kk] = (_Float16)s1;
    Mt[(size_t)(j + 512) * 768 + kk] = (_Float16)s2;
}

__global__ __launch_bounds__(256) void wp4(
        const float* __restrict__ Wp,
        const float* __restrict__ b1, const float* __restrict__ b2,
        const float* __restrict__ b3, const float* __restrict__ bp,
        const float* __restrict__ bw2, const float* __restrict__ bw3a,
        const float* __restrict__ bw3b, const float* __restrict__ bw3c,
        float* __restrict__ u1, float* __restrict__ u2,
        float* __restrict__ u3, float* __restrict__ c0) {
    int vec = blockIdx.x / 3, chunk = blockIdx.x % 3;
    int j = chunk * 256 + threadIdx.x;
    const float* P1 = Wp;
    const float* P2 = Wp + (size_t)256 * 768;
    const float* P3 = Wp + (size_t)512 * 768;
    float s = 0.f;
    if (vec == 0) {        // u1 = bw2@P2 + bw3a@P3
#pragma unroll 8
        for (int k = 0; k < 256; ++k) s += bw2[k] * P2[(size_t)k * 768 + j];
#pragma unroll 8
        for (int k = 0; k < 256; ++k) s += bw3a[k] * P3[(size_t)k * 768 + j];
        u1[j] = s;
    } else if (vec == 1) { // u2 = bw3b@P3
#pragma unroll 8
        for (int k = 0; k < 256; ++k) s += bw3b[k] * P3[(size_t)k * 768 + j];
        u2[j] = s;
    } else if (vec == 2) { // u3 = bw3c@P3
#pragma unroll 8
        for (int k = 0; k < 256; ++k) s += bw3c[k] * P3[(size_t)k * 768 + j];
        u3[j] = s;
    } else {               // c0 = b1@P1 + b2@P2 + b3@P3 + bp
#pragma unroll 8
        for (int k = 0; k < 256; ++k) s += b1[k] * P1[(size_t)k * 768 + j];
#pragma unroll 8
        for (int k = 0; k < 256; ++k) s += b2[k] * P2[(size_t)k * 768 + j];
#pragma unroll 8
        for (int k = 0; k < 256; ++k) s += b3[k] * P3[(size_t)k * 768 + j];
        c0[j] = s + bp[j];
    }
}

// ---------------------------------------------------------------------------
// MFMA GEMM: C[M,768] = A[M,768](fp16) @ B (fp16, given as Bt[n][k])
//            + rank-1 epilogue (c0 + R1 u1 + R2 u2 + R3 u3), fp32 out.
// 128x128 tile, 4 waves x (4x4 of mfma_f32_16x16x32_f16).
// v3: grid is launched over NPAD rows (392x6 = 2352 blocks, 2352 % 8 == 0)
//     so the XCD-chunked swizzle below is BIJECTIVE (round-1 bug: 391-row
//     launch left 6 pair-slots unproduced -> 6 output tiles never written).
//     Padded row-tile (rows 50000..50175) reads garbage from the padded
//     Acat region (allocated, never OOB) and all its stores are guarded by
//     gr >= M.
//     (a) XCD-chunked swizzle: the 6 same-bm blocks become consecutive
//         slots of ONE XCD -> each A-tile fetched by exactly one L2.
//     (b) double-buffered LDS staging: stage(t+1) issued before compute(t),
//         ONE __syncthreads per K-step (its implicit vmcnt(0)/lgkmcnt(0)
//         drain is the pipeline wait).
// ---------------------------------------------------------------------------
__device__ inline void g2lds16(const void* g, void* l) {
    __builtin_amdgcn_global_load_lds(
        (__attribute__((address_space(1))) void*)g,
        (__attribute__((address_space(3))) void*)l, 16, 0, 0);
}

__global__ __launch_bounds__(256) void gemm_mfma(
        const _Float16* __restrict__ A,   // [NPAD][768]
        const _Float16* __restrict__ Bt,  // [768][768], Bt[n][k]
        float* __restrict__ C, int M,
        const float* __restrict__ R1, const float* __restrict__ R2,
        const float* __restrict__ R3,
        const float* __restrict__ u1, const float* __restrict__ u2,
        const float* __restrict__ u3, const float* __restrict__ c0) {
    __shared__ _Float16 As[2][128 * 32];
    __shared__ _Float16 Bs[2][128 * 32];
    const int tid  = threadIdx.x;
    const int wid  = tid >> 6;
    const int lane = tid & 63;
    // XCD-chunked swizzle (bijective: 2352 % 8 == 0, 294 blocks per XCD).
    const int lid  = blockIdx.y * (DOUT / 128) + blockIdx.x;
    const int pair = (lid & 7) * (NPAD / 128 * (DOUT / 128) / 8) + (lid >> 3);
    const int bm = (pair / (DOUT / 128)) * 128;
    const int bn = (pair % (DOUT / 128)) * 128;
    const int wm = (wid >> 1) * 64;
    const int wn = (wid & 1) * 64;
    const int l15  = lane & 15;
    const int quad = lane >> 4;

    f32x4 acc[4][4] = {};

    const int srow_in_grp = lane >> 2;       // 0..15
    const int schunk      = lane & 3;        // physical 16B chunk this lane fills

    auto stage = [&](int buf, int k0) {
#pragma unroll
        for (int q = 0; q < 2; ++q) {
            int row = wid * 32 + q * 16 + srow_in_grp;             // 0..127
            int gchunk = (schunk - ((row >> 1) & 3)) & 3;          // global k-chunk
            const _Float16* ga = A  + (size_t)(bm + row) * DOUT + k0 + gchunk * 8;
            const _Float16* gb = Bt + (size_t)(bn + row) * DOUT + k0 + gchunk * 8;
            g2lds16(ga, &As[buf][(size_t)(wid * 32 + q * 16) * 32]);
            g2lds16(gb, &Bs[buf][(size_t)(wid * 32 + q * 16) * 32]);
        }
    };

    const int NT = DOUT / 32;   // 24 K-steps
    stage(0, 0);
    __syncthreads();            // drains vmcnt(0): buf0 ready
    int cur = 0;
    for (int t = 0; t < NT; ++t) {
        if (t + 1 < NT) stage(cur ^ 1, (t + 1) * 32);   // prefetch next K-step
        half8 af[4], bfr[4];
#pragma unroll
        for (int i = 0; i < 4; ++i) {
            int ra = wm + i * 16 + l15;
            int pa = (quad + ((ra >> 1) & 3)) & 3;
            af[i] = *(const half8*)(&As[cur][(size_t)ra * 32 + pa * 8]);
            int rb = wn + i * 16 + l15;
            int pb = (quad + ((rb >> 1) & 3)) & 3;
            bfr[i] = *(const half8*)(&Bs[cur][(size_t)rb * 32 + pb * 8]);
        }
#pragma unroll
        for (int mi = 0; mi < 4; ++mi)
#pragma unroll
            for (int ni = 0; ni < 4; ++ni)
                acc[mi][ni] = __builtin_amdgcn_mfma_f32_16x16x32_f16(
                    af[mi], bfr[ni], acc[mi][ni], 0, 0, 0);
        // one barrier per step: its implicit vmcnt(0)+lgkmcnt(0) drain makes
        // the prefetched buffer valid AND protects buf[cur] from overwrite.
        __syncthreads();
        cur ^= 1;
    }

    float e0[4], e1[4], e2[4], e3[4];
#pragma unroll
    for (int ni = 0; ni < 4; ++ni) {
        int gc = bn + wn + ni * 16 + l15;
        e0[ni] = c0[gc]; e1[ni] = u1[gc]; e2[ni] = u2[gc]; e3[ni] = u3[gc];
    }
#pragma unroll
    for (int mi = 0; mi < 4; ++mi) {
#pragma unroll
        for (int r = 0; r < 4; ++r) {
            int gr = bm + wm + mi * 16 + quad * 4 + r;
            if (gr >= M) continue;
            float r1 = R1[gr], r2 = R2[gr], r3 = R3[gr];
#pragma unroll
            for (int ni = 0; ni < 4; ++ni) {
                int gc = bn + wn + ni * 16 + l15;
                C[(size_t)gr * DOUT + gc] =
                    acc[mi][ni][r] + e0[ni] + r1 * e1[ni] + r2 * e2[ni] + r3 * e3[ni];
            }
        }
    }
}

// ---------------------------------------------------------------------------
// Fused LayerNorm + exact GELU, in-place. One block per row.
// ---------------------------------------------------------------------------
__global__ __launch_bounds__(256) void ln_gelu_kernel(float* __restrict__ out,
        const float* __restrict__ gamma, const float* __restrict__ beta) {
    int row = blockIdx.x;
    int t = threadIdx.x;
    float* p = out + (size_t)row * DOUT;
    float x0 = p[t], x1 = p[t + 256], x2 = p[t + 512];
    float s = x0 + x1 + x2;
    float s2 = x0 * x0 + x1 * x1 + x2 * x2;
    __shared__ float red[8];
    int wave = t >> 6, lane = t & 63;
#pragma unroll
    for (int m = 1; m < 64; m <<= 1) {
        s += __shfl_xor(s, m);
        s2 += __shfl_xor(s2, m);
    }
    if (lane == 0) { red[wave] = s; red[4 + wave] = s2; }
    __syncthreads();
    float S = red[0] + red[1] + red[2] + red[3];
    float S2 = red[4] + red[5] + red[6] + red[7];
    float mu = S * (1.f / 768.f);
    float var = S2 * (1.f / 768.f) - mu * mu;
    float inv = rsqrtf(var + 1e-5f);
    const float kk = 0.70710678118654752f;
#pragma unroll
    for (int i = 0; i < 3; ++i) {
        int c = t + 256 * i;
        float x = (i == 0) ? x0 : (i == 1) ? x1 : x2;
        float y = (x - mu) * inv * gamma[c] + beta[c];
        p[c] = 0.5f * y * (1.f + erff(y * kk));
    }
}

// ---------------------------------------------------------------------------
// Launch
// ---------------------------------------------------------------------------
extern "C" void kernel_launch(void* const* d_in, const int* in_sizes, int n_in,
                              void* d_out, int out_size, void* d_ws, size_t ws_size,
                              hipStream_t stream) {
    const float* x     = (const float*)d_in[0];
    const int*   ei    = (const int*)d_in[1];
    const float* ea    = (const float*)d_in[2];
    const float* W1    = (const float*)d_in[3];
    const float* b1    = (const float*)d_in[4];
    const float* W2    = (const float*)d_in[5];
    const float* b2    = (const float*)d_in[6];
    const float* W3    = (const float*)d_in[7];
    const float* b3    = (const float*)d_in[8];
    const float* Wp    = (const float*)d_in[9];
    const float* bp    = (const float*)d_in[10];
    const float* gamma = (const float*)d_in[11];
    const float* beta  = (const float*)d_in[12];
    float* out = (float*)d_out;

    char* w = (char*)d_ws;
    auto alloc = [&](size_t bytes) -> void* {
        void* p = (void*)w;
        w += (bytes + 255) & ~(size_t)255;
        return p;
    };
    _Float16* Acat = (_Float16*)alloc((size_t)NPAD * DOUT * 2);  // 77 MB  G1|G2|G4
    _Float16* Xh   = (_Float16*)alloc((size_t)NN * DIN * 2);     // 25 MB
    _Float16* G3h  = (_Float16*)alloc((size_t)NN * DIN * 2);     // 25 MB
    _Float16* Mt   = (_Float16*)alloc((size_t)DOUT * DOUT * 2);  // 1.2 MB
    int*   col    = (int*)alloc((size_t)NE * 4);
    float* val    = (float*)alloc((size_t)NE * 4);
    float* deg    = (float*)alloc((size_t)NN * 4);
    float* dinv   = (float*)alloc((size_t)NN * 4);
    int*   cnt    = (int*)alloc((size_t)NN * 4);
    int*   rowp   = (int*)alloc((size_t)(NN + 1) * 4);
    int*   cursor = (int*)alloc((size_t)NN * 4);
    float* R1     = (float*)alloc((size_t)NN * 4);
    float* R2     = (float*)alloc((size_t)NN * 4);
    float* R3     = (float*)alloc((size_t)NN * 4);
    float* W2sq   = (float*)alloc(256 * 256 * 4);
    float* W3_2   = (float*)alloc(256 * 256 * 4);
    float* W3_4   = (float*)alloc(256 * 256 * 4);
    float* bw2    = (float*)alloc(256 * 4);
    float* bw3a   = (float*)alloc(256 * 4);
    float* bw3b   = (float*)alloc(256 * 4);
    float* bw3c   = (float*)alloc(256 * 4);
    float* u1     = (float*)alloc(768 * 4);
    float* u2     = (float*)alloc(768 * 4);
    float* u3     = (float*)alloc(768 * 4);
    float* c0     = (float*)alloc(768 * 4);

    const int nb_n = (NN + 255) / 256;
    const int nb_e = (NE + 255) / 256;

    // degree + CSR
    init_deg_cnt<<<nb_n, 256, 0, stream>>>(deg, cnt);
    edge_deg_cnt<<<nb_e, 256, 0, stream>>>(ei, ea, deg, cnt);
    compute_dinv<<<nb_n, 256, 0, stream>>>(deg, dinv);
    scan_kernel<<<1, 1024, 0, stream>>>(cnt, rowp, cursor);
    edge_scatter<<<nb_e, 256, 0, stream>>>(ei, ea, dinv, cursor, col, val);

    // x -> fp16
    x2h_kernel<<<(NN * DIN / 4 + 255) / 256, 256, 0, stream>>>(x, Xh);

    // weight-side precompute, 4 launches
    wp1<<<514, 256, 0, stream>>>(W2, W3, b2, b3, W2sq, W3_2, bw2, bw3a);
    wp2<<<257, 256, 0, stream>>>(W3_2, W3, bw3a, W3_4, bw3b);
    wp3<<<769, 256, 0, stream>>>(W1, W2sq, W3_4, Wp, W3, bw3b, Mt, bw3c);
    wp4<<<12, 256, 0, stream>>>(Wp, b1, b2, b3, bp, bw2, bw3a, bw3b, bw3c,
                                u1, u2, u3, c0);

    // shared aggregation chain: G1=Ax, G2=A G1, G3=A G2, G4=A G3 (+ R chain)
    const int nb_a = (NN + 3) / 4;
    agg_kernel<<<nb_a, 256, 0, stream>>>(Xh, DIN,          Acat + 0,   DOUT, nullptr, R1, rowp, col, val, dinv);
    agg_kernel<<<nb_a, 256, 0, stream>>>(Acat + 0,   DOUT, Acat + 256, DOUT, R1,      R2, rowp, col, val, dinv);
    agg_kernel<<<nb_a, 256, 0, stream>>>(Acat + 256, DOUT, G3h,        DIN,  R2,      R3, rowp, col, val, dinv);
    agg_kernel<<<nb_a, 256, 0, stream>>>(G3h,        DIN,  Acat + 512, DOUT, nullptr, nullptr, rowp, col, val, dinv);

    // fused projection GEMM (fp16 MFMA) + bias epilogue
    // NOTE: grid covers NPAD rows (392), NOT ceil(NN/128)=391 — required for
    // the bijective XCD swizzle (2352 % 8 == 0). Do not "optimize" back.
    dim3 grid(DOUT / 128, NPAD / 128);
    gemm_mfma<<<grid, 256, 0, stream>>>(Acat, Mt, out, NN, R1, R2, R3, u1, u2, u3, c0);

    // LayerNorm + exact GELU in-place
    ln_gelu_kernel<<<NN, 256, 0, stream>>>(out, gamma, beta);
}

// Round 3
// 860.780 us; speedup vs baseline: 1.1310x; 1.1310x over previous
//
#include <hip/hip_runtime.h>
#include <math.h>

#define NN 50000        // nodes
#define NE 800000       // edges
#define DIN 256
#define DOUT 768
#define NPAD 50176      // NN padded to multiple of 128 for GEMM tile staging
#define NBS 196         // ceil(NN/256) blocks for the hierarchical scan

typedef _Float16 half8 __attribute__((ext_vector_type(8)));
typedef _Float16 half4 __attribute__((ext_vector_type(4)));
typedef float    f32x4 __attribute__((ext_vector_type(4)));

// ---------------------------------------------------------------------------
// Degree / CSR construction
// ---------------------------------------------------------------------------
__global__ void init_deg_cnt(float* __restrict__ deg, int* __restrict__ cnt) {
    int i = blockIdx.x * 256 + threadIdx.x;
    if (i < NN) { deg[i] = 1.0f; cnt[i] = 0; }   // self-loop weight 1 pre-added
}

__global__ void edge_deg_cnt(const int* __restrict__ ei, const float* __restrict__ ea,
                             float* __restrict__ deg, int* __restrict__ cnt) {
    int e = blockIdx.x * 256 + threadIdx.x;
    if (e >= NE) return;
    int dst = ei[NE + e];
    atomicAdd(&deg[dst], ea[e]);
    atomicAdd(&cnt[dst], 1);
}

__global__ void compute_dinv(const float* __restrict__ deg, float* __restrict__ dinv) {
    int i = blockIdx.x * 256 + threadIdx.x;
    if (i < NN) { float d = deg[i]; dinv[i] = d > 0.f ? rsqrtf(d) : 0.f; }
}

// ---------------------------------------------------------------------------
// Hierarchical scan (replaces the 116 us single-block scan_kernel):
//   scan_bsum:  196 blocks, coalesced block sums
//   scan_boff:  1 block, exclusive scan of the 196 block sums
//   scan_write: 196 blocks, block-local exclusive scan + offset -> rowp/cursor
// Integer arithmetic -> bit-identical rowp to the serial version.
// ---------------------------------------------------------------------------
__global__ __launch_bounds__(256) void scan_bsum(const int* __restrict__ cnt,
                                                 int* __restrict__ bsum) {
    int i = blockIdx.x * 256 + threadIdx.x;
    int v = (i < NN) ? cnt[i] : 0;
#pragma unroll
    for (int m = 1; m < 64; m <<= 1) v += __shfl_xor(v, m);
    __shared__ int ws[4];
    int wave = threadIdx.x >> 6, lane = threadIdx.x & 63;
    if (lane == 0) ws[wave] = v;
    __syncthreads();
    if (threadIdx.x == 0) bsum[blockIdx.x] = ws[0] + ws[1] + ws[2] + ws[3];
}

__global__ __launch_bounds__(256) void scan_boff(const int* __restrict__ bsum,
                                                 int* __restrict__ boff) {
    int t = threadIdx.x;
    int v = (t < NBS) ? bsum[t] : 0;
    int lane = t & 63, wave = t >> 6, orig = v;
#pragma unroll
    for (int d = 1; d < 64; d <<= 1) {
        int u = __shfl_up(v, d);
        if (lane >= d) v += u;
    }
    __shared__ int ws[4];
    if (lane == 63) ws[wave] = v;
    __syncthreads();
    int wp = 0;
#pragma unroll
    for (int w2 = 0; w2 < 4; ++w2) if (w2 < wave) wp += ws[w2];
    if (t < NBS) boff[t] = wp + v - orig;   // exclusive prefix
}

__global__ __launch_bounds__(256) void scan_write(const int* __restrict__ cnt,
                                                  const int* __restrict__ boff,
                                                  int* __restrict__ rowp,
                                                  int* __restrict__ cursor) {
    int b = blockIdx.x, t = threadIdx.x;
    int i = b * 256 + t;
    int v = (i < NN) ? cnt[i] : 0;
    int lane = t & 63, wave = t >> 6, orig = v;
#pragma unroll
    for (int d = 1; d < 64; d <<= 1) {
        int u = __shfl_up(v, d);
        if (lane >= d) v += u;
    }
    __shared__ int ws[4];
    if (lane == 63) ws[wave] = v;
    __syncthreads();
    int wp = 0;
#pragma unroll
    for (int w2 = 0; w2 < 4; ++w2) if (w2 < wave) wp += ws[w2];
    int excl = boff[b] + wp + v - orig;
    if (i < NN) { rowp[i] = excl; cursor[i] = excl; }
    if (i == NN - 1) rowp[NN] = NE;
}

__global__ void edge_scatter(const int* __restrict__ ei, const float* __restrict__ ea,
                             const float* __restrict__ dinv, int* __restrict__ cursor,
                             int* __restrict__ col, float* __restrict__ val) {
    int e = blockIdx.x * 256 + threadIdx.x;
    if (e >= NE) return;
    int s = ei[e];
    int d = ei[NE + e];
    int pos = atomicAdd(&cursor[d], 1);
    col[pos] = s;
    val[pos] = dinv[s] * ea[e] * dinv[d];
}

// convert x fp32 -> fp16 (4 elems/thread)
__global__ void x2h_kernel(const float* __restrict__ x, _Float16* __restrict__ Xh) {
    int i = blockIdx.x * 256 + threadIdx.x;
    if (i >= NN * DIN / 4) return;
    float4 v = ((const float4*)x)[i];
    half4 h; h[0] = (_Float16)v.x; h[1] = (_Float16)v.y;
    h[2] = (_Float16)v.z; h[3] = (_Float16)v.w;
    ((half4*)Xh)[i] = h;
}

__device__ inline float rv(const float* __restrict__ R, int c) {
    return R ? R[c] : 1.f;
}

// ---------------------------------------------------------------------------
// Aggregation, fp16 in / fp16 out, fp32 accumulate. One WAVE per node.
// Row = 256 fp16 = 512 B = 64 lanes x 8 B (full-wave gather). 8 edges in
// flight per wave. (Round-2 A/B: 4->8 MLP was ~neutral -> agg is bound by
// random-access L2/L3 throughput, not MLP; kept as-is this round.)
// ---------------------------------------------------------------------------
__global__ __launch_bounds__(256) void agg_kernel(
        const _Float16* __restrict__ Gin, int sIn,
        _Float16* __restrict__ Gout, int sOut,
        const float* __restrict__ Rin, float* __restrict__ Rout,
        const int* __restrict__ rowp, const int* __restrict__ colv,
        const float* __restrict__ val, const float* __restrict__ dinv) {
    int node = blockIdx.x * 4 + (threadIdx.x >> 6);
    if (node >= NN) return;
    int lane = threadIdx.x & 63;
    const _Float16* gb = Gin + lane * 4;
    float acc[4] = {0.f, 0.f, 0.f, 0.f};
    float racc = 0.f;
    int beg = rowp[node], end = rowp[node + 1];
    int k = beg;
    for (; k + 8 <= end; k += 8) {
        int   c0 = colv[k+0], c1 = colv[k+1], c2 = colv[k+2], c3 = colv[k+3];
        int   c4 = colv[k+4], c5 = colv[k+5], c6 = colv[k+6], c7 = colv[k+7];
        float v0 = val[k+0], v1 = val[k+1], v2 = val[k+2], v3 = val[k+3];
        float v4 = val[k+4], v5 = val[k+5], v6 = val[k+6], v7 = val[k+7];
        half4 g0 = *(const half4*)(gb + (size_t)c0 * sIn);
        half4 g1 = *(const half4*)(gb + (size_t)c1 * sIn);
        half4 g2 = *(const half4*)(gb + (size_t)c2 * sIn);
        half4 g3 = *(const half4*)(gb + (size_t)c3 * sIn);
        half4 g4 = *(const half4*)(gb + (size_t)c4 * sIn);
        half4 g5 = *(const half4*)(gb + (size_t)c5 * sIn);
        half4 g6 = *(const half4*)(gb + (size_t)c6 * sIn);
        half4 g7 = *(const half4*)(gb + (size_t)c7 * sIn);
#pragma unroll
        for (int j = 0; j < 4; ++j)
            acc[j] += v0 * (float)g0[j] + v1 * (float)g1[j]
                    + v2 * (float)g2[j] + v3 * (float)g3[j]
                    + v4 * (float)g4[j] + v5 * (float)g5[j]
                    + v6 * (float)g6[j] + v7 * (float)g7[j];
        if (Rout)
            racc += v0 * rv(Rin, c0) + v1 * rv(Rin, c1)
                  + v2 * rv(Rin, c2) + v3 * rv(Rin, c3)
                  + v4 * rv(Rin, c4) + v5 * rv(Rin, c5)
                  + v6 * rv(Rin, c6) + v7 * rv(Rin, c7);
    }
    for (; k + 4 <= end; k += 4) {
        int   c0 = colv[k+0], c1 = colv[k+1], c2 = colv[k+2], c3 = colv[k+3];
        float v0 = val[k+0], v1 = val[k+1], v2 = val[k+2], v3 = val[k+3];
        half4 g0 = *(const half4*)(gb + (size_t)c0 * sIn);
        half4 g1 = *(const half4*)(gb + (size_t)c1 * sIn);
        half4 g2 = *(const half4*)(gb + (size_t)c2 * sIn);
        half4 g3 = *(const half4*)(gb + (size_t)c3 * sIn);
#pragma unroll
        for (int j = 0; j < 4; ++j)
            acc[j] += v0 * (float)g0[j] + v1 * (float)g1[j]
                    + v2 * (float)g2[j] + v3 * (float)g3[j];
        if (Rout)
            racc += v0 * rv(Rin, c0) + v1 * rv(Rin, c1)
                  + v2 * rv(Rin, c2) + v3 * rv(Rin, c3);
    }
    for (; k < end; ++k) {
        int c = colv[k]; float v = val[k];
        half4 g = *(const half4*)(gb + (size_t)c * sIn);
#pragma unroll
        for (int j = 0; j < 4; ++j) acc[j] += v * (float)g[j];
        if (Rout) racc += v * rv(Rin, c);
    }
    float dv = dinv[node], sv = dv * dv;
    half4 gs = *(const half4*)(gb + (size_t)node * sIn);
#pragma unroll
    for (int j = 0; j < 4; ++j) acc[j] += sv * (float)gs[j];
    half4 o;
#pragma unroll
    for (int j = 0; j < 4; ++j) o[j] = (_Float16)acc[j];
    *(half4*)(Gout + (size_t)node * sOut + lane * 4) = o;
    if (Rout && lane == 0)
        Rout[node] = racc + sv * (Rin ? Rin[node] : 1.f);
}

// ---------------------------------------------------------------------------
// Weight-side precompute, consolidated into 4 launches.
// ---------------------------------------------------------------------------
__global__ __launch_bounds__(256) void wp1(
        const float* __restrict__ W2, const float* __restrict__ W3,
        const float* __restrict__ b2, const float* __restrict__ b3,
        float* __restrict__ W2sq, float* __restrict__ W3_2,
        float* __restrict__ bw2, float* __restrict__ bw3a) {
    int b = blockIdx.x, j = threadIdx.x;
    const float* A; const float* B; float* C;
    if (b < 256)      { A = W2 + b * 256;         B = W2; C = W2sq + b * 256; }
    else if (b < 512) { A = W3 + (b - 256) * 256; B = W3; C = W3_2 + (b - 256) * 256; }
    else if (b == 512){ A = b2;                   B = W2; C = bw2; }
    else              { A = b3;                   B = W3; C = bw3a; }
    float s = 0.f;
#pragma unroll 8
    for (int k = 0; k < 256; ++k) s += A[k] * B[k * 256 + j];
    C[j] = s;
}

__global__ __launch_bounds__(256) void wp2(
        const float* __restrict__ W3_2, const float* __restrict__ W3,
        const float* __restrict__ bw3a,
        float* __restrict__ W3_4, float* __restrict__ bw3b) {
    int b = blockIdx.x, j = threadIdx.x;
    const float* A; const float* B; float* C;
    if (b < 256) { A = W3_2 + b * 256; B = W3_2; C = W3_4 + b * 256; }
    else         { A = bw3a;           B = W3;   C = bw3b; }
    float s = 0.f;
#pragma unroll 8
    for (int k = 0; k < 256; ++k) s += A[k] * B[k * 256 + j];
    C[j] = s;
}

__global__ __launch_bounds__(256) void wp3(
        const float* __restrict__ W1, const float* __restrict__ W2sq,
        const float* __restrict__ W3_4, const float* __restrict__ Wp,
        const float* __restrict__ W3, const float* __restrict__ bw3b,
        _Float16* __restrict__ Mt, float* __restrict__ bw3c) {
    int b = blockIdx.x, j = threadIdx.x;
    if (b == 768) {   // bw3c = bw3b @ W3
        float s = 0.f;
#pragma unroll 8
        for (int k = 0; k < 256; ++k) s += bw3b[k] * W3[k * 256 + j];
        bw3c[j] = s;
        return;
    }
    int kk = b;                       // output row of Mcat = column of Mt
    int blk = kk >> 8;                // 0,1,2
    const float* A = (blk == 0) ? (W1 + kk * 256)
                   : (blk == 1) ? (W2sq + (kk - 256) * 256)
                                : (W3_4 + (kk - 512) * 256);
    const float* B = Wp + (size_t)(blk * 256) * 768;
    float s0 = 0.f, s1 = 0.f, s2 = 0.f;
#pragma unroll 4
    for (int m = 0; m < 256; ++m) {
        float a = A[m];
        const float* br = B + (size_t)m * 768;
        s0 += a * br[j]; s1 += a * br[j + 256]; s2 += a * br[j + 512];
    }
    // Mt[n][k] = Mcat[k][n]
    Mt[(size_t)j * 768 + kk]         = (_Float16)s0;
    Mt[(size_t)(j + 256) * 768 + kk] = (_Float16)s1;
    Mt[(size_t)(j + 512) * 768 + kk] = (_Float16)s2;
}

__global__ __launch_bounds__(256) void wp4(
        const float* __restrict__ Wp,
        const float* __restrict__ b1, const float* __restrict__ b2,
        const float* __restrict__ b3, const float* __restrict__ bp,
        const float* __restrict__ bw2, const float* __restrict__ bw3a,
        const float* __restrict__ bw3b, const float* __restrict__ bw3c,
        float* __restrict__ u1, float* __restrict__ u2,
        float* __restrict__ u3, float* __restrict__ c0) {
    int vec = blockIdx.x / 3, chunk = blockIdx.x % 3;
    int j = chunk * 256 + threadIdx.x;
    const float* P1 = Wp;
    const float* P2 = Wp + (size_t)256 * 768;
    const float* P3 = Wp + (size_t)512 * 768;
    float s = 0.f;
    if (vec == 0) {        // u1 = bw2@P2 + bw3a@P3
#pragma unroll 8
        for (int k = 0; k < 256; ++k) s += bw2[k] * P2[(size_t)k * 768 + j];
#pragma unroll 8
        for (int k = 0; k < 256; ++k) s += bw3a[k] * P3[(size_t)k * 768 + j];
        u1[j] = s;
    } else if (vec == 1) { // u2 = bw3b@P3
#pragma unroll 8
        for (int k = 0; k < 256; ++k) s += bw3b[k] * P3[(size_t)k * 768 + j];
        u2[j] = s;
    } else if (vec == 2) { // u3 = bw3c@P3
#pragma unroll 8
        for (int k = 0; k < 256; ++k) s += bw3c[k] * P3[(size_t)k * 768 + j];
        u3[j] = s;
    } else {               // c0 = b1@P1 + b2@P2 + b3@P3 + bp
#pragma unroll 8
        for (int k = 0; k < 256; ++k) s += b1[k] * P1[(size_t)k * 768 + j];
#pragma unroll 8
        for (int k = 0; k < 256; ++k) s += b2[k] * P2[(size_t)k * 768 + j];
#pragma unroll 8
        for (int k = 0; k < 256; ++k) s += b3[k] * P3[(size_t)k * 768 + j];
        c0[j] = s + bp[j];
    }
}

// ---------------------------------------------------------------------------
// MFMA GEMM: C[M,768] = A[M,768](fp16) @ B (fp16, given as Bt[n][k])
//            + rank-1 epilogue (c0 + R1 u1 + R2 u2 + R3 u3), fp32 out.
// 128x128 tile, 4 waves x (4x4 of mfma_f32_16x16x32_f16).
// v4: BK=64 (12 K-steps, 32 MFMA per barrier) — halves the number of
//     vmcnt(0)+barrier drains vs BK=32, doubling the compute each drain is
//     amortized over (gemm was pipeline-stall bound: MfmaUtil 21%, hbm 22%).
//     LDS 64 KB (2 blocks/CU). Per-row 16B-chunk ROTATION swizzle: LDS row
//     r holds logical chunk (p - r) & 7 at physical chunk p; stage pre-
//     rotates the GLOBAL source address (global_load_lds dest must stay
//     linear), ds_read applies the same rotation.
//     Grid stays over NPAD rows (392x6 = 2352, 2352 % 8 == 0) for the
//     bijective XCD-chunked swizzle. Do not "optimize" back to 391.
// ---------------------------------------------------------------------------
__device__ inline void g2lds16(const void* g, void* l) {
    __builtin_amdgcn_global_load_lds(
        (__attribute__((address_space(1))) void*)g,
        (__attribute__((address_space(3))) void*)l, 16, 0, 0);
}

__global__ __launch_bounds__(256) void gemm_mfma(
        const _Float16* __restrict__ A,   // [NPAD][768]
        const _Float16* __restrict__ Bt,  // [768][768], Bt[n][k]
        float* __restrict__ C, int M,
        const float* __restrict__ R1, const float* __restrict__ R2,
        const float* __restrict__ R3,
        const float* __restrict__ u1, const float* __restrict__ u2,
        const float* __restrict__ u3, const float* __restrict__ c0) {
    __shared__ _Float16 As[2][128 * 64];   // 32 KB
    __shared__ _Float16 Bs[2][128 * 64];   // 32 KB
    const int tid  = threadIdx.x;
    const int wid  = tid >> 6;
    const int lane = tid & 63;
    // XCD-chunked swizzle (bijective: 2352 % 8 == 0, 294 blocks per XCD).
    const int lid  = blockIdx.y * (DOUT / 128) + blockIdx.x;
    const int pair = (lid & 7) * (NPAD / 128 * (DOUT / 128) / 8) + (lid >> 3);
    const int bm = (pair / (DOUT / 128)) * 128;
    const int bn = (pair % (DOUT / 128)) * 128;
    const int wm = (wid >> 1) * 64;
    const int wn = (wid & 1) * 64;
    const int l15  = lane & 15;
    const int quad = lane >> 4;

    f32x4 acc[4][4] = {};

    // Staging: per wave-issue, 64 lanes x 16B = 1 KB = 8 rows x 128 B.
    // lane l covers row (base + l>>3), physical chunk (l&7); LDS dest is
    // linear (base_row*128 + l*16), global src pre-rotated by the swizzle.
    auto stage = [&](int buf, int k0) {
#pragma unroll
        for (int it = 0; it < 4; ++it) {
            int row = wid * 32 + it * 8 + (lane >> 3);      // 0..127
            int lc  = ((lane & 7) - row) & 7;               // logical chunk
            const _Float16* ga = A  + (size_t)(bm + row) * DOUT + k0 + lc * 8;
            const _Float16* gb = Bt + (size_t)(bn + row) * DOUT + k0 + lc * 8;
            g2lds16(ga, &As[buf][(size_t)(wid * 32 + it * 8) * 64]);
            g2lds16(gb, &Bs[buf][(size_t)(wid * 32 + it * 8) * 64]);
        }
    };

    const int NT = DOUT / 64;   // 12 K-steps
    stage(0, 0);
    __syncthreads();            // drains vmcnt(0): buf0 ready
    int cur = 0;
    for (int t = 0; t < NT; ++t) {
        if (t + 1 < NT) stage(cur ^ 1, (t + 1) * 64);   // prefetch next K-step
        half8 af[2][4], bf[2][4];
#pragma unroll
        for (int i = 0; i < 4; ++i) {
            int ra = wm + i * 16 + l15;
            int rb = wn + i * 16 + l15;
#pragma unroll
            for (int h = 0; h < 2; ++h) {
                int pa = ((h * 4 + quad) + ra) & 7;
                af[h][i] = *(const half8*)(&As[cur][(size_t)ra * 64 + pa * 8]);
                int pb = ((h * 4 + quad) + rb) & 7;
                bf[h][i] = *(const half8*)(&Bs[cur][(size_t)rb * 64 + pb * 8]);
            }
        }
#pragma unroll
        for (int mi = 0; mi < 4; ++mi)
#pragma unroll
            for (int ni = 0; ni < 4; ++ni) {
                acc[mi][ni] = __builtin_amdgcn_mfma_f32_16x16x32_f16(
                    af[0][mi], bf[0][ni], acc[mi][ni], 0, 0, 0);
                acc[mi][ni] = __builtin_amdgcn_mfma_f32_16x16x32_f16(
                    af[1][mi], bf[1][ni], acc[mi][ni], 0, 0, 0);
            }
        // one barrier per step: its implicit vmcnt(0)+lgkmcnt(0) drain makes
        // the prefetched buffer valid AND protects buf[cur] from overwrite.
        __syncthreads();
        cur ^= 1;
    }

    float e0[4], e1[4], e2[4], e3[4];
#pragma unroll
    for (int ni = 0; ni < 4; ++ni) {
        int gc = bn + wn + ni * 16 + l15;
        e0[ni] = c0[gc]; e1[ni] = u1[gc]; e2[ni] = u2[gc]; e3[ni] = u3[gc];
    }
#pragma unroll
    for (int mi = 0; mi < 4; ++mi) {
#pragma unroll
        for (int r = 0; r < 4; ++r) {
            int gr = bm + wm + mi * 16 + quad * 4 + r;
            if (gr >= M) continue;
            float r1 = R1[gr], r2 = R2[gr], r3 = R3[gr];
#pragma unroll
            for (int ni = 0; ni < 4; ++ni) {
                int gc = bn + wn + ni * 16 + l15;
                C[(size_t)gr * DOUT + gc] =
                    acc[mi][ni][r] + e0[ni] + r1 * e1[ni] + r2 * e2[ni] + r3 * e3[ni];
            }
        }
    }
}

// ---------------------------------------------------------------------------
// Fused LayerNorm + exact GELU, in-place. One block per row.
// ---------------------------------------------------------------------------
__global__ __launch_bounds__(256) void ln_gelu_kernel(float* __restrict__ out,
        const float* __restrict__ gamma, const float* __restrict__ beta) {
    int row = blockIdx.x;
    int t = threadIdx.x;
    float* p = out + (size_t)row * DOUT;
    float x0 = p[t], x1 = p[t + 256], x2 = p[t + 512];
    float s = x0 + x1 + x2;
    float s2 = x0 * x0 + x1 * x1 + x2 * x2;
    __shared__ float red[8];
    int wave = t >> 6, lane = t & 63;
#pragma unroll
    for (int m = 1; m < 64; m <<= 1) {
        s += __shfl_xor(s, m);
        s2 += __shfl_xor(s2, m);
    }
    if (lane == 0) { red[wave] = s; red[4 + wave] = s2; }
    __syncthreads();
    float S = red[0] + red[1] + red[2] + red[3];
    float S2 = red[4] + red[5] + red[6] + red[7];
    float mu = S * (1.f / 768.f);
    float var = S2 * (1.f / 768.f) - mu * mu;
    float inv = rsqrtf(var + 1e-5f);
    const float kk = 0.70710678118654752f;
#pragma unroll
    for (int i = 0; i < 3; ++i) {
        int c = t + 256 * i;
        float x = (i == 0) ? x0 : (i == 1) ? x1 : x2;
        float y = (x - mu) * inv * gamma[c] + beta[c];
        p[c] = 0.5f * y * (1.f + erff(y * kk));
    }
}

// ---------------------------------------------------------------------------
// Launch
// ---------------------------------------------------------------------------
extern "C" void kernel_launch(void* const* d_in, const int* in_sizes, int n_in,
                              void* d_out, int out_size, void* d_ws, size_t ws_size,
                              hipStream_t stream) {
    const float* x     = (const float*)d_in[0];
    const int*   ei    = (const int*)d_in[1];
    const float* ea    = (const float*)d_in[2];
    const float* W1    = (const float*)d_in[3];
    const float* b1    = (const float*)d_in[4];
    const float* W2    = (const float*)d_in[5];
    const float* b2    = (const float*)d_in[6];
    const float* W3    = (const float*)d_in[7];
    const float* b3    = (const float*)d_in[8];
    const float* Wp    = (const float*)d_in[9];
    const float* bp    = (const float*)d_in[10];
    const float* gamma = (const float*)d_in[11];
    const float* beta  = (const float*)d_in[12];
    float* out = (float*)d_out;

    char* w = (char*)d_ws;
    auto alloc = [&](size_t bytes) -> void* {
        void* p = (void*)w;
        w += (bytes + 255) & ~(size_t)255;
        return p;
    };
    _Float16* Acat = (_Float16*)alloc((size_t)NPAD * DOUT * 2);  // 77 MB  G1|G2|G4
    _Float16* Xh   = (_Float16*)alloc((size_t)NN * DIN * 2);     // 25 MB
    _Float16* G3h  = (_Float16*)alloc((size_t)NN * DIN * 2);     // 25 MB
    _Float16* Mt   = (_Float16*)alloc((size_t)DOUT * DOUT * 2);  // 1.2 MB
    int*   col    = (int*)alloc((size_t)NE * 4);
    float* val    = (float*)alloc((size_t)NE * 4);
    float* deg    = (float*)alloc((size_t)NN * 4);
    float* dinv   = (float*)alloc((size_t)NN * 4);
    int*   cnt    = (int*)alloc((size_t)NN * 4);
    int*   rowp   = (int*)alloc((size_t)(NN + 1) * 4);
    int*   cursor = (int*)alloc((size_t)NN * 4);
    int*   bsum   = (int*)alloc((size_t)NBS * 4);
    int*   boff   = (int*)alloc((size_t)NBS * 4);
    float* R1     = (float*)alloc((size_t)NN * 4);
    float* R2     = (float*)alloc((size_t)NN * 4);
    float* R3     = (float*)alloc((size_t)NN * 4);
    float* W2sq   = (float*)alloc(256 * 256 * 4);
    float* W3_2   = (float*)alloc(256 * 256 * 4);
    float* W3_4   = (float*)alloc(256 * 256 * 4);
    float* bw2    = (float*)alloc(256 * 4);
    float* bw3a   = (float*)alloc(256 * 4);
    float* bw3b   = (float*)alloc(256 * 4);
    float* bw3c   = (float*)alloc(256 * 4);
    float* u1     = (float*)alloc(768 * 4);
    float* u2     = (float*)alloc(768 * 4);
    float* u3     = (float*)alloc(768 * 4);
    float* c0     = (float*)alloc(768 * 4);

    const int nb_n = (NN + 255) / 256;
    const int nb_e = (NE + 255) / 256;

    // degree + CSR (hierarchical scan)
    init_deg_cnt<<<nb_n, 256, 0, stream>>>(deg, cnt);
    edge_deg_cnt<<<nb_e, 256, 0, stream>>>(ei, ea, deg, cnt);
    compute_dinv<<<nb_n, 256, 0, stream>>>(deg, dinv);
    scan_bsum<<<NBS, 256, 0, stream>>>(cnt, bsum);
    scan_boff<<<1, 256, 0, stream>>>(bsum, boff);
    scan_write<<<NBS, 256, 0, stream>>>(cnt, boff, rowp, cursor);
    edge_scatter<<<nb_e, 256, 0, stream>>>(ei, ea, dinv, cursor, col, val);

    // x -> fp16
    x2h_kernel<<<(NN * DIN / 4 + 255) / 256, 256, 0, stream>>>(x, Xh);

    // weight-side precompute, 4 launches
    wp1<<<514, 256, 0, stream>>>(W2, W3, b2, b3, W2sq, W3_2, bw2, bw3a);
    wp2<<<257, 256, 0, stream>>>(W3_2, W3, bw3a, W3_4, bw3b);
    wp3<<<769, 256, 0, stream>>>(W1, W2sq, W3_4, Wp, W3, bw3b, Mt, bw3c);
    wp4<<<12, 256, 0, stream>>>(Wp, b1, b2, b3, bp, bw2, bw3a, bw3b, bw3c,
                                u1, u2, u3, c0);

    // shared aggregation chain: G1=Ax, G2=A G1, G3=A G2, G4=A G3 (+ R chain)
    const int nb_a = (NN + 3) / 4;
    agg_kernel<<<nb_a, 256, 0, stream>>>(Xh, DIN,          Acat + 0,   DOUT, nullptr, R1, rowp, col, val, dinv);
    agg_kernel<<<nb_a, 256, 0, stream>>>(Acat + 0,   DOUT, Acat + 256, DOUT, R1,      R2, rowp, col, val, dinv);
    agg_kernel<<<nb_a, 256, 0, stream>>>(Acat + 256, DOUT, G3h,        DIN,  R2,      R3, rowp, col, val, dinv);
    agg_kernel<<<nb_a, 256, 0, stream>>>(G3h,        DIN,  Acat + 512, DOUT, nullptr, nullptr, rowp, col, val, dinv);

    // fused projection GEMM (fp16 MFMA) + bias epilogue
    // NOTE: grid covers NPAD rows (392), NOT ceil(NN/128)=391 — required for
    // the bijective XCD swizzle (2352 % 8 == 0). Do not "optimize" back.
    dim3 grid(DOUT / 128, NPAD / 128);
    gemm_mfma<<<grid, 256, 0, stream>>>(Acat, Mt, out, NN, R1, R2, R3, u1, u2, u3, c0);

    // LayerNorm + exact GELU in-place
    ln_gelu_kernel<<<NN, 256, 0, stream>>>(out, gamma, beta);
}

// Round 4
// 815.811 us; speedup vs baseline: 1.1934x; 1.0551x over previous
//
#include <hip/hip_runtime.h>
#include <math.h>

#define NN 50000        // nodes
#define NE 800000       // edges
#define DIN 256
#define DOUT 768
#define NPAD 50176      // NN padded to multiple of 128 for GEMM tile staging
#define NBS 196         // ceil(NN/256) blocks for the hierarchical scan

typedef _Float16 half8 __attribute__((ext_vector_type(8)));
typedef _Float16 half4 __attribute__((ext_vector_type(4)));
typedef float    f32x4 __attribute__((ext_vector_type(4)));

// ---------------------------------------------------------------------------
// Degree / CSR construction
// ---------------------------------------------------------------------------
__global__ void init_deg_cnt(float* __restrict__ deg, int* __restrict__ cnt) {
    int i = blockIdx.x * 256 + threadIdx.x;
    if (i < NN) { deg[i] = 1.0f; cnt[i] = 0; }   // self-loop weight 1 pre-added
}

__global__ void edge_deg_cnt(const int* __restrict__ ei, const float* __restrict__ ea,
                             float* __restrict__ deg, int* __restrict__ cnt) {
    int e = blockIdx.x * 256 + threadIdx.x;
    if (e >= NE) return;
    int dst = ei[NE + e];
    atomicAdd(&deg[dst], ea[e]);
    atomicAdd(&cnt[dst], 1);
}

__global__ void compute_dinv(const float* __restrict__ deg, float* __restrict__ dinv) {
    int i = blockIdx.x * 256 + threadIdx.x;
    if (i < NN) { float d = deg[i]; dinv[i] = d > 0.f ? rsqrtf(d) : 0.f; }
}

// ---------------------------------------------------------------------------
// Hierarchical scan: scan_bsum (196 blocks) -> scan_boff (1 block) ->
// scan_write (196 blocks). Bit-identical rowp to the serial version.
// ---------------------------------------------------------------------------
__global__ __launch_bounds__(256) void scan_bsum(const int* __restrict__ cnt,
                                                 int* __restrict__ bsum) {
    int i = blockIdx.x * 256 + threadIdx.x;
    int v = (i < NN) ? cnt[i] : 0;
#pragma unroll
    for (int m = 1; m < 64; m <<= 1) v += __shfl_xor(v, m);
    __shared__ int ws[4];
    int wave = threadIdx.x >> 6, lane = threadIdx.x & 63;
    if (lane == 0) ws[wave] = v;
    __syncthreads();
    if (threadIdx.x == 0) bsum[blockIdx.x] = ws[0] + ws[1] + ws[2] + ws[3];
}

__global__ __launch_bounds__(256) void scan_boff(const int* __restrict__ bsum,
                                                 int* __restrict__ boff) {
    int t = threadIdx.x;
    int v = (t < NBS) ? bsum[t] : 0;
    int lane = t & 63, wave = t >> 6, orig = v;
#pragma unroll
    for (int d = 1; d < 64; d <<= 1) {
        int u = __shfl_up(v, d);
        if (lane >= d) v += u;
    }
    __shared__ int ws[4];
    if (lane == 63) ws[wave] = v;
    __syncthreads();
    int wp = 0;
#pragma unroll
    for (int w2 = 0; w2 < 4; ++w2) if (w2 < wave) wp += ws[w2];
    if (t < NBS) boff[t] = wp + v - orig;   // exclusive prefix
}

__global__ __launch_bounds__(256) void scan_write(const int* __restrict__ cnt,
                                                  const int* __restrict__ boff,
                                                  int* __restrict__ rowp,
                                                  int* __restrict__ cursor) {
    int b = blockIdx.x, t = threadIdx.x;
    int i = b * 256 + t;
    int v = (i < NN) ? cnt[i] : 0;
    int lane = t & 63, wave = t >> 6, orig = v;
#pragma unroll
    for (int d = 1; d < 64; d <<= 1) {
        int u = __shfl_up(v, d);
        if (lane >= d) v += u;
    }
    __shared__ int ws[4];
    if (lane == 63) ws[wave] = v;
    __syncthreads();
    int wp = 0;
#pragma unroll
    for (int w2 = 0; w2 < 4; ++w2) if (w2 < wave) wp += ws[w2];
    int excl = boff[b] + wp + v - orig;
    if (i < NN) { rowp[i] = excl; cursor[i] = excl; }
    if (i == NN - 1) rowp[NN] = NE;
}

__global__ void edge_scatter(const int* __restrict__ ei, const float* __restrict__ ea,
                             const float* __restrict__ dinv, int* __restrict__ cursor,
                             int* __restrict__ col, float* __restrict__ val) {
    int e = blockIdx.x * 256 + threadIdx.x;
    if (e >= NE) return;
    int s = ei[e];
    int d = ei[NE + e];
    int pos = atomicAdd(&cursor[d], 1);
    col[pos] = s;
    val[pos] = dinv[s] * ea[e] * dinv[d];
}

// convert x fp32 -> fp16 (4 elems/thread)
__global__ void x2h_kernel(const float* __restrict__ x, _Float16* __restrict__ Xh) {
    int i = blockIdx.x * 256 + threadIdx.x;
    if (i >= NN * DIN / 4) return;
    float4 v = ((const float4*)x)[i];
    half4 h; h[0] = (_Float16)v.x; h[1] = (_Float16)v.y;
    h[2] = (_Float16)v.z; h[3] = (_Float16)v.w;
    ((half4*)Xh)[i] = h;
}

__device__ inline float rv(const float* __restrict__ R, int c) {
    return R ? R[c] : 1.f;
}

// ---------------------------------------------------------------------------
// Aggregation, fp16 in / fp16 out, fp32 accumulate. One WAVE per node.
// Row = 256 fp16 = 512 B = 64 lanes x 8 B (full-wave gather). 8 edges in
// flight per wave. (Round-2 A/B: 4->8 MLP neutral -> not MLP-bound; leading
// theory: L3-bound random gathers. Counters land next round when gemm drops
// below agg in the top-5.)
// ---------------------------------------------------------------------------
__global__ __launch_bounds__(256) void agg_kernel(
        const _Float16* __restrict__ Gin, int sIn,
        _Float16* __restrict__ Gout, int sOut,
        const float* __restrict__ Rin, float* __restrict__ Rout,
        const int* __restrict__ rowp, const int* __restrict__ colv,
        const float* __restrict__ val, const float* __restrict__ dinv) {
    int node = blockIdx.x * 4 + (threadIdx.x >> 6);
    if (node >= NN) return;
    int lane = threadIdx.x & 63;
    const _Float16* gb = Gin + lane * 4;
    float acc[4] = {0.f, 0.f, 0.f, 0.f};
    float racc = 0.f;
    int beg = rowp[node], end = rowp[node + 1];
    int k = beg;
    for (; k + 8 <= end; k += 8) {
        int   c0 = colv[k+0], c1 = colv[k+1], c2 = colv[k+2], c3 = colv[k+3];
        int   c4 = colv[k+4], c5 = colv[k+5], c6 = colv[k+6], c7 = colv[k+7];
        float v0 = val[k+0], v1 = val[k+1], v2 = val[k+2], v3 = val[k+3];
        float v4 = val[k+4], v5 = val[k+5], v6 = val[k+6], v7 = val[k+7];
        half4 g0 = *(const half4*)(gb + (size_t)c0 * sIn);
        half4 g1 = *(const half4*)(gb + (size_t)c1 * sIn);
        half4 g2 = *(const half4*)(gb + (size_t)c2 * sIn);
        half4 g3 = *(const half4*)(gb + (size_t)c3 * sIn);
        half4 g4 = *(const half4*)(gb + (size_t)c4 * sIn);
        half4 g5 = *(const half4*)(gb + (size_t)c5 * sIn);
        half4 g6 = *(const half4*)(gb + (size_t)c6 * sIn);
        half4 g7 = *(const half4*)(gb + (size_t)c7 * sIn);
#pragma unroll
        for (int j = 0; j < 4; ++j)
            acc[j] += v0 * (float)g0[j] + v1 * (float)g1[j]
                    + v2 * (float)g2[j] + v3 * (float)g3[j]
                    + v4 * (float)g4[j] + v5 * (float)g5[j]
                    + v6 * (float)g6[j] + v7 * (float)g7[j];
        if (Rout)
            racc += v0 * rv(Rin, c0) + v1 * rv(Rin, c1)
                  + v2 * rv(Rin, c2) + v3 * rv(Rin, c3)
                  + v4 * rv(Rin, c4) + v5 * rv(Rin, c5)
                  + v6 * rv(Rin, c6) + v7 * rv(Rin, c7);
    }
    for (; k + 4 <= end; k += 4) {
        int   c0 = colv[k+0], c1 = colv[k+1], c2 = colv[k+2], c3 = colv[k+3];
        float v0 = val[k+0], v1 = val[k+1], v2 = val[k+2], v3 = val[k+3];
        half4 g0 = *(const half4*)(gb + (size_t)c0 * sIn);
        half4 g1 = *(const half4*)(gb + (size_t)c1 * sIn);
        half4 g2 = *(const half4*)(gb + (size_t)c2 * sIn);
        half4 g3 = *(const half4*)(gb + (size_t)c3 * sIn);
#pragma unroll
        for (int j = 0; j < 4; ++j)
            acc[j] += v0 * (float)g0[j] + v1 * (float)g1[j]
                    + v2 * (float)g2[j] + v3 * (float)g3[j];
        if (Rout)
            racc += v0 * rv(Rin, c0) + v1 * rv(Rin, c1)
                  + v2 * rv(Rin, c2) + v3 * rv(Rin, c3);
    }
    for (; k < end; ++k) {
        int c = colv[k]; float v = val[k];
        half4 g = *(const half4*)(gb + (size_t)c * sIn);
#pragma unroll
        for (int j = 0; j < 4; ++j) acc[j] += v * (float)g[j];
        if (Rout) racc += v * rv(Rin, c);
    }
    float dv = dinv[node], sv = dv * dv;
    half4 gs = *(const half4*)(gb + (size_t)node * sIn);
#pragma unroll
    for (int j = 0; j < 4; ++j) acc[j] += sv * (float)gs[j];
    half4 o;
#pragma unroll
    for (int j = 0; j < 4; ++j) o[j] = (_Float16)acc[j];
    *(half4*)(Gout + (size_t)node * sOut + lane * 4) = o;
    if (Rout && lane == 0)
        Rout[node] = racc + sv * (Rin ? Rin[node] : 1.f);
}

// ---------------------------------------------------------------------------
// Weight-side precompute, consolidated into 4 launches.
// ---------------------------------------------------------------------------
__global__ __launch_bounds__(256) void wp1(
        const float* __restrict__ W2, const float* __restrict__ W3,
        const float* __restrict__ b2, const float* __restrict__ b3,
        float* __restrict__ W2sq, float* __restrict__ W3_2,
        float* __restrict__ bw2, float* __restrict__ bw3a) {
    int b = blockIdx.x, j = threadIdx.x;
    const float* A; const float* B; float* C;
    if (b < 256)      { A = W2 + b * 256;         B = W2; C = W2sq + b * 256; }
    else if (b < 512) { A = W3 + (b - 256) * 256; B = W3; C = W3_2 + (b - 256) * 256; }
    else if (b == 512){ A = b2;                   B = W2; C = bw2; }
    else              { A = b3;                   B = W3; C = bw3a; }
    float s = 0.f;
#pragma unroll 8
    for (int k = 0; k < 256; ++k) s += A[k] * B[k * 256 + j];
    C[j] = s;
}

__global__ __launch_bounds__(256) void wp2(
        const float* __restrict__ W3_2, const float* __restrict__ W3,
        const float* __restrict__ bw3a,
        float* __restrict__ W3_4, float* __restrict__ bw3b) {
    int b = blockIdx.x, j = threadIdx.x;
    const float* A; const float* B; float* C;
    if (b < 256) { A = W3_2 + b * 256; B = W3_2; C = W3_4 + b * 256; }
    else         { A = bw3a;           B = W3;   C = bw3b; }
    float s = 0.f;
#pragma unroll 8
    for (int k = 0; k < 256; ++k) s += A[k] * B[k * 256 + j];
    C[j] = s;
}

__global__ __launch_bounds__(256) void wp3(
        const float* __restrict__ W1, const float* __restrict__ W2sq,
        const float* __restrict__ W3_4, const float* __restrict__ Wp,
        const float* __restrict__ W3, const float* __restrict__ bw3b,
        _Float16* __restrict__ Mt, float* __restrict__ bw3c) {
    int b = blockIdx.x, j = threadIdx.x;
    if (b == 768) {   // bw3c = bw3b @ W3
        float s = 0.f;
#pragma unroll 8
        for (int k = 0; k < 256; ++k) s += bw3b[k] * W3[k * 256 + j];
        bw3c[j] = s;
        return;
    }
    int kk = b;                       // output row of Mcat = column of Mt
    int blk = kk >> 8;                // 0,1,2
    const float* A = (blk == 0) ? (W1 + kk * 256)
                   : (blk == 1) ? (W2sq + (kk - 256) * 256)
                                : (W3_4 + (kk - 512) * 256);
    const float* B = Wp + (size_t)(blk * 256) * 768;
    float s0 = 0.f, s1 = 0.f, s2 = 0.f;
#pragma unroll 4
    for (int m = 0; m < 256; ++m) {
        float a = A[m];
        const float* br = B + (size_t)m * 768;
        s0 += a * br[j]; s1 += a * br[j + 256]; s2 += a * br[j + 512];
    }
    // Mt[n][k] = Mcat[k][n]
    Mt[(size_t)j * 768 + kk]         = (_Float16)s0;
    Mt[(size_t)(j + 256) * 768 + kk] = (_Float16)s1;
    Mt[(size_t)(j + 512) * 768 + kk] = (_Float16)s2;
}

__global__ __launch_bounds__(256) void wp4(
        const float* __restrict__ Wp,
        const float* __restrict__ b1, const float* __restrict__ b2,
        const float* __restrict__ b3, const float* __restrict__ bp,
        const float* __restrict__ bw2, const float* __restrict__ bw3a,
        const float* __restrict__ bw3b, const float* __restrict__ bw3c,
        float* __restrict__ u1, float* __restrict__ u2,
        float* __restrict__ u3, float* __restrict__ c0) {
    int vec = blockIdx.x / 3, chunk = blockIdx.x % 3;
    int j = chunk * 256 + threadIdx.x;
    const float* P1 = Wp;
    const float* P2 = Wp + (size_t)256 * 768;
    const float* P3 = Wp + (size_t)512 * 768;
    float s = 0.f;
    if (vec == 0) {        // u1 = bw2@P2 + bw3a@P3
#pragma unroll 8
        for (int k = 0; k < 256; ++k) s += bw2[k] * P2[(size_t)k * 768 + j];
#pragma unroll 8
        for (int k = 0; k < 256; ++k) s += bw3a[k] * P3[(size_t)k * 768 + j];
        u1[j] = s;
    } else if (vec == 1) { // u2 = bw3b@P3
#pragma unroll 8
        for (int k = 0; k < 256; ++k) s += bw3b[k] * P3[(size_t)k * 768 + j];
        u2[j] = s;
    } else if (vec == 2) { // u3 = bw3c@P3
#pragma unroll 8
        for (int k = 0; k < 256; ++k) s += bw3c[k] * P3[(size_t)k * 768 + j];
        u3[j] = s;
    } else {               // c0 = b1@P1 + b2@P2 + b3@P3 + bp
#pragma unroll 8
        for (int k = 0; k < 256; ++k) s += b1[k] * P1[(size_t)k * 768 + j];
#pragma unroll 8
        for (int k = 0; k < 256; ++k) s += b2[k] * P2[(size_t)k * 768 + j];
#pragma unroll 8
        for (int k = 0; k < 256; ++k) s += b3[k] * P3[(size_t)k * 768 + j];
        c0[j] = s + bp[j];
    }
}

// ---------------------------------------------------------------------------
// MFMA GEMM: Ch[M,768](fp16) = A[M,768](fp16) @ B + rank-1 epilogue.
// 128x128 tile, 4 waves x (4x4 of mfma_f32_16x16x32_f16), BK=64, dbuf.
// v5: counted-vmcnt pipeline (T4). Per K-step:
//       stage(nxt)                      // 8 global_load_lds, stay in flight
//       s_waitcnt vmcnt(8)              // drain ONLY the 8 older (cur) loads
//       s_barrier                       // raw: no vmcnt(0) drain!
//       ds_read cur + 32 MFMA
//       s_barrier                       // readers done -> cur may be overwritten
//     Round-3's __syncthreads drained vmcnt(0) each step, killing the
//     prefetch (MfmaUtil 22.6%). sched_barrier(0) fences pin the order
//     (guide m152/m218 discipline).
//     Output is fp16 (halves WRITE_SIZE; LN reads half the bytes).
//     Grid stays over NPAD rows (392x6 = 2352 % 8 == 0) for the bijective
//     XCD-chunked swizzle. Do not "optimize" back to 391.
// ---------------------------------------------------------------------------
__device__ inline void g2lds16(const void* g, void* l) {
    __builtin_amdgcn_global_load_lds(
        (__attribute__((address_space(1))) void*)g,
        (__attribute__((address_space(3))) void*)l, 16, 0, 0);
}

__global__ __launch_bounds__(256) void gemm_mfma(
        const _Float16* __restrict__ A,   // [NPAD][768]
        const _Float16* __restrict__ Bt,  // [768][768], Bt[n][k]
        _Float16* __restrict__ Ch, int M,
        const float* __restrict__ R1, const float* __restrict__ R2,
        const float* __restrict__ R3,
        const float* __restrict__ u1, const float* __restrict__ u2,
        const float* __restrict__ u3, const float* __restrict__ c0) {
    __shared__ _Float16 As[2][128 * 64];   // 32 KB
    __shared__ _Float16 Bs[2][128 * 64];   // 32 KB
    const int tid  = threadIdx.x;
    const int wid  = tid >> 6;
    const int lane = tid & 63;
    // XCD-chunked swizzle (bijective: 2352 % 8 == 0, 294 blocks per XCD).
    const int lid  = blockIdx.y * (DOUT / 128) + blockIdx.x;
    const int pair = (lid & 7) * (NPAD / 128 * (DOUT / 128) / 8) + (lid >> 3);
    const int bm = (pair / (DOUT / 128)) * 128;
    const int bn = (pair % (DOUT / 128)) * 128;
    const int wm = (wid >> 1) * 64;
    const int wn = (wid & 1) * 64;
    const int l15  = lane & 15;
    const int quad = lane >> 4;

    f32x4 acc[4][4] = {};

    // Staging: per stage() call, each thread issues 8 global_load_lds (16 B).
    // LDS dest linear; global src pre-rotated by the per-row chunk swizzle.
    auto stage = [&](int buf, int k0) {
#pragma unroll
        for (int it = 0; it < 4; ++it) {
            int row = wid * 32 + it * 8 + (lane >> 3);      // 0..127
            int lc  = ((lane & 7) - row) & 7;               // logical chunk
            const _Float16* ga = A  + (size_t)(bm + row) * DOUT + k0 + lc * 8;
            const _Float16* gb = Bt + (size_t)(bn + row) * DOUT + k0 + lc * 8;
            g2lds16(ga, &As[buf][(size_t)(wid * 32 + it * 8) * 64]);
            g2lds16(gb, &Bs[buf][(size_t)(wid * 32 + it * 8) * 64]);
        }
    };

    const int NT = DOUT / 64;   // 12 K-steps
    stage(0, 0);                // 8 loads in flight for buf0
    int cur = 0;
    for (int t = 0; t < NT; ++t) {
        if (t + 1 < NT) {
            stage(cur ^ 1, (t + 1) * 64);   // +8 loads for nxt (stay in flight)
            __builtin_amdgcn_sched_barrier(0);
            asm volatile("s_waitcnt vmcnt(8)" ::: "memory");  // cur loads done
        } else {
            asm volatile("s_waitcnt vmcnt(0)" ::: "memory");  // last tile
        }
        __builtin_amdgcn_s_barrier();       // all waves' cur-writes visible
        __builtin_amdgcn_sched_barrier(0);
        half8 af[2][4], bf[2][4];
#pragma unroll
        for (int i = 0; i < 4; ++i) {
            int ra = wm + i * 16 + l15;
            int rb = wn + i * 16 + l15;
#pragma unroll
            for (int h = 0; h < 2; ++h) {
                int pa = ((h * 4 + quad) + ra) & 7;
                af[h][i] = *(const half8*)(&As[cur][(size_t)ra * 64 + pa * 8]);
                int pb = ((h * 4 + quad) + rb) & 7;
                bf[h][i] = *(const half8*)(&Bs[cur][(size_t)rb * 64 + pb * 8]);
            }
        }
#pragma unroll
        for (int mi = 0; mi < 4; ++mi)
#pragma unroll
            for (int ni = 0; ni < 4; ++ni) {
                acc[mi][ni] = __builtin_amdgcn_mfma_f32_16x16x32_f16(
                    af[0][mi], bf[0][ni], acc[mi][ni], 0, 0, 0);
                acc[mi][ni] = __builtin_amdgcn_mfma_f32_16x16x32_f16(
                    af[1][mi], bf[1][ni], acc[mi][ni], 0, 0, 0);
            }
        __builtin_amdgcn_sched_barrier(0);
        __builtin_amdgcn_s_barrier();       // all waves done READING cur
        cur ^= 1;
    }

    float e0[4], e1[4], e2[4], e3[4];
#pragma unroll
    for (int ni = 0; ni < 4; ++ni) {
        int gc = bn + wn + ni * 16 + l15;
        e0[ni] = c0[gc]; e1[ni] = u1[gc]; e2[ni] = u2[gc]; e3[ni] = u3[gc];
    }
#pragma unroll
    for (int mi = 0; mi < 4; ++mi) {
#pragma unroll
        for (int r = 0; r < 4; ++r) {
            int gr = bm + wm + mi * 16 + quad * 4 + r;
            if (gr >= M) continue;
            float r1 = R1[gr], r2 = R2[gr], r3 = R3[gr];
#pragma unroll
            for (int ni = 0; ni < 4; ++ni) {
                int gc = bn + wn + ni * 16 + l15;
                Ch[(size_t)gr * DOUT + gc] = (_Float16)(
                    acc[mi][ni][r] + e0[ni] + r1 * e1[ni] + r2 * e2[ni] + r3 * e3[ni]);
            }
        }
    }
}

// ---------------------------------------------------------------------------
// Fused LayerNorm + exact GELU: fp16 in (Ch), fp32 out. One WAVE per row,
// no block barrier. Lane holds 12 elems (3 x half4), wave shfl reduce.
// ---------------------------------------------------------------------------
__global__ __launch_bounds__(256) void ln_gelu_kernel(
        const _Float16* __restrict__ Ch, float* __restrict__ out,
        const float* __restrict__ gamma, const float* __restrict__ beta) {
    int row = blockIdx.x * 4 + (threadIdx.x >> 6);
    if (row >= NN) return;
    int lane = threadIdx.x & 63;
    const _Float16* p = Ch + (size_t)row * DOUT;
    half4 h0 = *(const half4*)(p + lane * 4);
    half4 h1 = *(const half4*)(p + 256 + lane * 4);
    half4 h2 = *(const half4*)(p + 512 + lane * 4);
    float v[12];
#pragma unroll
    for (int j = 0; j < 4; ++j) {
        v[j]     = (float)h0[j];
        v[4 + j] = (float)h1[j];
        v[8 + j] = (float)h2[j];
    }
    float s = 0.f, s2 = 0.f;
#pragma unroll
    for (int j = 0; j < 12; ++j) { s += v[j]; s2 += v[j] * v[j]; }
#pragma unroll
    for (int m = 1; m < 64; m <<= 1) {
        s += __shfl_xor(s, m);
        s2 += __shfl_xor(s2, m);
    }
    float mu = s * (1.f / 768.f);
    float var = s2 * (1.f / 768.f) - mu * mu;
    float inv = rsqrtf(var + 1e-5f);
    const float kk = 0.70710678118654752f;
    float* po = out + (size_t)row * DOUT;
#pragma unroll
    for (int i = 0; i < 3; ++i) {
        int c = i * 256 + lane * 4;
        float4 g = *(const float4*)(gamma + c);
        float4 b = *(const float4*)(beta + c);
        float4 o;
        float y0 = (v[i * 4 + 0] - mu) * inv * g.x + b.x;
        float y1 = (v[i * 4 + 1] - mu) * inv * g.y + b.y;
        float y2 = (v[i * 4 + 2] - mu) * inv * g.z + b.z;
        float y3 = (v[i * 4 + 3] - mu) * inv * g.w + b.w;
        o.x = 0.5f * y0 * (1.f + erff(y0 * kk));
        o.y = 0.5f * y1 * (1.f + erff(y1 * kk));
        o.z = 0.5f * y2 * (1.f + erff(y2 * kk));
        o.w = 0.5f * y3 * (1.f + erff(y3 * kk));
        *(float4*)(po + c) = o;
    }
}

// ---------------------------------------------------------------------------
// Launch
// ---------------------------------------------------------------------------
extern "C" void kernel_launch(void* const* d_in, const int* in_sizes, int n_in,
                              void* d_out, int out_size, void* d_ws, size_t ws_size,
                              hipStream_t stream) {
    const float* x     = (const float*)d_in[0];
    const int*   ei    = (const int*)d_in[1];
    const float* ea    = (const float*)d_in[2];
    const float* W1    = (const float*)d_in[3];
    const float* b1    = (const float*)d_in[4];
    const float* W2    = (const float*)d_in[5];
    const float* b2    = (const float*)d_in[6];
    const float* W3    = (const float*)d_in[7];
    const float* b3    = (const float*)d_in[8];
    const float* Wp    = (const float*)d_in[9];
    const float* bp    = (const float*)d_in[10];
    const float* gamma = (const float*)d_in[11];
    const float* beta  = (const float*)d_in[12];
    float* out = (float*)d_out;

    char* w = (char*)d_ws;
    auto alloc = [&](size_t bytes) -> void* {
        void* p = (void*)w;
        w += (bytes + 255) & ~(size_t)255;
        return p;
    };
    _Float16* Acat = (_Float16*)alloc((size_t)NPAD * DOUT * 2);  // 77 MB  G1|G2|G4
    _Float16* Xh   = (_Float16*)alloc((size_t)NN * DIN * 2);     // 25 MB
    _Float16* G3h  = (_Float16*)alloc((size_t)NN * DIN * 2);     // 25 MB
    _Float16* Ch   = (_Float16*)alloc((size_t)NN * DOUT * 2);    // 77 MB
    _Float16* Mt   = (_Float16*)alloc((size_t)DOUT * DOUT * 2);  // 1.2 MB
    int*   col    = (int*)alloc((size_t)NE * 4);
    float* val    = (float*)alloc((size_t)NE * 4);
    float* deg    = (float*)alloc((size_t)NN * 4);
    float* dinv   = (float*)alloc((size_t)NN * 4);
    int*   cnt    = (int*)alloc((size_t)NN * 4);
    int*   rowp   = (int*)alloc((size_t)(NN + 1) * 4);
    int*   cursor = (int*)alloc((size_t)NN * 4);
    int*   bsum   = (int*)alloc((size_t)NBS * 4);
    int*   boff   = (int*)alloc((size_t)NBS * 4);
    float* R1     = (float*)alloc((size_t)NN * 4);
    float* R2     = (float*)alloc((size_t)NN * 4);
    float* R3     = (float*)alloc((size_t)NN * 4);
    float* W2sq   = (float*)alloc(256 * 256 * 4);
    float* W3_2   = (float*)alloc(256 * 256 * 4);
    float* W3_4   = (float*)alloc(256 * 256 * 4);
    float* bw2    = (float*)alloc(256 * 4);
    float* bw3a   = (float*)alloc(256 * 4);
    float* bw3b   = (float*)alloc(256 * 4);
    float* bw3c   = (float*)alloc(256 * 4);
    float* u1     = (float*)alloc(768 * 4);
    float* u2     = (float*)alloc(768 * 4);
    float* u3     = (float*)alloc(768 * 4);
    float* c0     = (float*)alloc(768 * 4);

    const int nb_n = (NN + 255) / 256;
    const int nb_e = (NE + 255) / 256;

    // degree + CSR (hierarchical scan)
    init_deg_cnt<<<nb_n, 256, 0, stream>>>(deg, cnt);
    edge_deg_cnt<<<nb_e, 256, 0, stream>>>(ei, ea, deg, cnt);
    compute_dinv<<<nb_n, 256, 0, stream>>>(deg, dinv);
    scan_bsum<<<NBS, 256, 0, stream>>>(cnt, bsum);
    scan_boff<<<1, 256, 0, stream>>>(bsum, boff);
    scan_write<<<NBS, 256, 0, stream>>>(cnt, boff, rowp, cursor);
    edge_scatter<<<nb_e, 256, 0, stream>>>(ei, ea, dinv, cursor, col, val);

    // x -> fp16
    x2h_kernel<<<(NN * DIN / 4 + 255) / 256, 256, 0, stream>>>(x, Xh);

    // weight-side precompute, 4 launches
    wp1<<<514, 256, 0, stream>>>(W2, W3, b2, b3, W2sq, W3_2, bw2, bw3a);
    wp2<<<257, 256, 0, stream>>>(W3_2, W3, bw3a, W3_4, bw3b);
    wp3<<<769, 256, 0, stream>>>(W1, W2sq, W3_4, Wp, W3, bw3b, Mt, bw3c);
    wp4<<<12, 256, 0, stream>>>(Wp, b1, b2, b3, bp, bw2, bw3a, bw3b, bw3c,
                                u1, u2, u3, c0);

    // shared aggregation chain: G1=Ax, G2=A G1, G3=A G2, G4=A G3 (+ R chain)
    const int nb_a = (NN + 3) / 4;
    agg_kernel<<<nb_a, 256, 0, stream>>>(Xh, DIN,          Acat + 0,   DOUT, nullptr, R1, rowp, col, val, dinv);
    agg_kernel<<<nb_a, 256, 0, stream>>>(Acat + 0,   DOUT, Acat + 256, DOUT, R1,      R2, rowp, col, val, dinv);
    agg_kernel<<<nb_a, 256, 0, stream>>>(Acat + 256, DOUT, G3h,        DIN,  R2,      R3, rowp, col, val, dinv);
    agg_kernel<<<nb_a, 256, 0, stream>>>(G3h,        DIN,  Acat + 512, DOUT, nullptr, nullptr, rowp, col, val, dinv);

    // fused projection GEMM (fp16 MFMA) + bias epilogue, fp16 output
    // NOTE: grid covers NPAD rows (392), NOT ceil(NN/128)=391 — required for
    // the bijective XCD swizzle (2352 % 8 == 0). Do not "optimize" back.
    dim3 grid(DOUT / 128, NPAD / 128);
    gemm_mfma<<<grid, 256, 0, stream>>>(Acat, Mt, Ch, NN, R1, R2, R3, u1, u2, u3, c0);

    // LayerNorm + exact GELU: fp16 in, fp32 out, wave-per-row
    ln_gelu_kernel<<<(NN + 3) / 4, 256, 0, stream>>>(Ch, out, gamma, beta);
}

// Round 5
// 809.735 us; speedup vs baseline: 1.2023x; 1.0075x over previous
//
#include <hip/hip_runtime.h>
#include <math.h>

#define NN 50000        // nodes
#define NE 800000       // edges
#define DIN 256
#define DOUT 768
#define NPAD 50176      // NN padded to multiple of 128 for GEMM tile staging
#define NBS 196         // ceil(NN/256) blocks for the hierarchical scan

typedef _Float16 half8 __attribute__((ext_vector_type(8)));
typedef _Float16 half4 __attribute__((ext_vector_type(4)));
typedef float    f32x4 __attribute__((ext_vector_type(4)));

// ---------------------------------------------------------------------------
// Degree / CSR construction
// ---------------------------------------------------------------------------
__global__ void init_deg_cnt(float* __restrict__ deg, int* __restrict__ cnt) {
    int i = blockIdx.x * 256 + threadIdx.x;
    if (i < NN) { deg[i] = 1.0f; cnt[i] = 0; }   // self-loop weight 1 pre-added
}

__global__ void edge_deg_cnt(const int* __restrict__ ei, const float* __restrict__ ea,
                             float* __restrict__ deg, int* __restrict__ cnt) {
    int e = blockIdx.x * 256 + threadIdx.x;
    if (e >= NE) return;
    int dst = ei[NE + e];
    atomicAdd(&deg[dst], ea[e]);
    atomicAdd(&cnt[dst], 1);
}

__global__ void compute_dinv(const float* __restrict__ deg, float* __restrict__ dinv) {
    int i = blockIdx.x * 256 + threadIdx.x;
    if (i < NN) { float d = deg[i]; dinv[i] = d > 0.f ? rsqrtf(d) : 0.f; }
}

// ---------------------------------------------------------------------------
// Hierarchical scan: scan_bsum (196 blocks) -> scan_boff (1 block) ->
// scan_write (196 blocks). Bit-identical rowp to the serial version.
// ---------------------------------------------------------------------------
__global__ __launch_bounds__(256) void scan_bsum(const int* __restrict__ cnt,
                                                 int* __restrict__ bsum) {
    int i = blockIdx.x * 256 + threadIdx.x;
    int v = (i < NN) ? cnt[i] : 0;
#pragma unroll
    for (int m = 1; m < 64; m <<= 1) v += __shfl_xor(v, m);
    __shared__ int ws[4];
    int wave = threadIdx.x >> 6, lane = threadIdx.x & 63;
    if (lane == 0) ws[wave] = v;
    __syncthreads();
    if (threadIdx.x == 0) bsum[blockIdx.x] = ws[0] + ws[1] + ws[2] + ws[3];
}

__global__ __launch_bounds__(256) void scan_boff(const int* __restrict__ bsum,
                                                 int* __restrict__ boff) {
    int t = threadIdx.x;
    int v = (t < NBS) ? bsum[t] : 0;
    int lane = t & 63, wave = t >> 6, orig = v;
#pragma unroll
    for (int d = 1; d < 64; d <<= 1) {
        int u = __shfl_up(v, d);
        if (lane >= d) v += u;
    }
    __shared__ int ws[4];
    if (lane == 63) ws[wave] = v;
    __syncthreads();
    int wp = 0;
#pragma unroll
    for (int w2 = 0; w2 < 4; ++w2) if (w2 < wave) wp += ws[w2];
    if (t < NBS) boff[t] = wp + v - orig;   // exclusive prefix
}

__global__ __launch_bounds__(256) void scan_write(const int* __restrict__ cnt,
                                                  const int* __restrict__ boff,
                                                  int* __restrict__ rowp,
                                                  int* __restrict__ cursor) {
    int b = blockIdx.x, t = threadIdx.x;
    int i = b * 256 + t;
    int v = (i < NN) ? cnt[i] : 0;
    int lane = t & 63, wave = t >> 6, orig = v;
#pragma unroll
    for (int d = 1; d < 64; d <<= 1) {
        int u = __shfl_up(v, d);
        if (lane >= d) v += u;
    }
    __shared__ int ws[4];
    if (lane == 63) ws[wave] = v;
    __syncthreads();
    int wp = 0;
#pragma unroll
    for (int w2 = 0; w2 < 4; ++w2) if (w2 < wave) wp += ws[w2];
    int excl = boff[b] + wp + v - orig;
    if (i < NN) { rowp[i] = excl; cursor[i] = excl; }
    if (i == NN - 1) rowp[NN] = NE;
}

__global__ void edge_scatter(const int* __restrict__ ei, const float* __restrict__ ea,
                             const float* __restrict__ dinv, int* __restrict__ cursor,
                             int* __restrict__ col, float* __restrict__ val) {
    int e = blockIdx.x * 256 + threadIdx.x;
    if (e >= NE) return;
    int s = ei[e];
    int d = ei[NE + e];
    int pos = atomicAdd(&cursor[d], 1);
    col[pos] = s;
    val[pos] = dinv[s] * ea[e] * dinv[d];
}

// convert x fp32 -> fp16 (4 elems/thread)
__global__ void x2h_kernel(const float* __restrict__ x, _Float16* __restrict__ Xh) {
    int i = blockIdx.x * 256 + threadIdx.x;
    if (i >= NN * DIN / 4) return;
    float4 v = ((const float4*)x)[i];
    half4 h; h[0] = (_Float16)v.x; h[1] = (_Float16)v.y;
    h[2] = (_Float16)v.z; h[3] = (_Float16)v.w;
    ((half4*)Xh)[i] = h;
}

__device__ inline float rv(const float* __restrict__ R, int c) {
    return R ? R[c] : 1.f;
}

// ---------------------------------------------------------------------------
// Aggregation, fp16 in / fp16 out, fp32 accumulate. One WAVE per node.
// Row = 256 fp16 = 512 B = 64 lanes x 8 B (full-wave gather).
// v6: avg degree = NE/NN = 16, so the old remainder path (4-wide group +
//     SERIAL singles, 1 gather in flight each) was latency-exposed on ~half
//     the edges. New: full-8 fast path (vectorizable col/val loads) + ONE
//     predicated 8-wide tail group (idx clamped to end-1 -> dup gathers are
//     L2-hot; v=0 masks pads). Every node = ceil(deg/8) fully-parallel
//     gather groups.
// ---------------------------------------------------------------------------
__global__ __launch_bounds__(256) void agg_kernel(
        const _Float16* __restrict__ Gin, int sIn,
        _Float16* __restrict__ Gout, int sOut,
        const float* __restrict__ Rin, float* __restrict__ Rout,
        const int* __restrict__ rowp, const int* __restrict__ colv,
        const float* __restrict__ val, const float* __restrict__ dinv) {
    int node = blockIdx.x * 4 + (threadIdx.x >> 6);
    if (node >= NN) return;
    int lane = threadIdx.x & 63;
    const _Float16* gb = Gin + lane * 4;
    float acc[4] = {0.f, 0.f, 0.f, 0.f};
    float racc = 0.f;
    int beg = rowp[node], end = rowp[node + 1];
    int k = beg;
    for (; k + 8 <= end; k += 8) {
        int c[8]; float vv[8]; half4 g[8];
#pragma unroll
        for (int j = 0; j < 8; ++j) c[j] = colv[k + j];
#pragma unroll
        for (int j = 0; j < 8; ++j) g[j] = *(const half4*)(gb + (size_t)c[j] * sIn);
#pragma unroll
        for (int j = 0; j < 8; ++j) vv[j] = val[k + j];
#pragma unroll
        for (int j = 0; j < 4; ++j)
            acc[j] += vv[0] * (float)g[0][j] + vv[1] * (float)g[1][j]
                    + vv[2] * (float)g[2][j] + vv[3] * (float)g[3][j]
                    + vv[4] * (float)g[4][j] + vv[5] * (float)g[5][j]
                    + vv[6] * (float)g[6][j] + vv[7] * (float)g[7][j];
        if (Rout)
#pragma unroll
            for (int j = 0; j < 8; ++j) racc += vv[j] * rv(Rin, c[j]);
    }
    if (k < end) {   // one predicated 8-wide tail group, full MLP
        int c[8]; float vv[8]; half4 g[8];
#pragma unroll
        for (int j = 0; j < 8; ++j) {
            int e = k + j;
            int es = e < end ? e : end - 1;       // valid: end-1 >= beg here
            c[j]  = colv[es];
            vv[j] = (e < end) ? val[es] : 0.f;
        }
#pragma unroll
        for (int j = 0; j < 8; ++j) g[j] = *(const half4*)(gb + (size_t)c[j] * sIn);
#pragma unroll
        for (int j = 0; j < 4; ++j)
            acc[j] += vv[0] * (float)g[0][j] + vv[1] * (float)g[1][j]
                    + vv[2] * (float)g[2][j] + vv[3] * (float)g[3][j]
                    + vv[4] * (float)g[4][j] + vv[5] * (float)g[5][j]
                    + vv[6] * (float)g[6][j] + vv[7] * (float)g[7][j];
        if (Rout)
#pragma unroll
            for (int j = 0; j < 8; ++j) racc += vv[j] * rv(Rin, c[j]);
    }
    float dv = dinv[node], sv = dv * dv;
    half4 gs = *(const half4*)(gb + (size_t)node * sIn);
#pragma unroll
    for (int j = 0; j < 4; ++j) acc[j] += sv * (float)gs[j];
    half4 o;
#pragma unroll
    for (int j = 0; j < 4; ++j) o[j] = (_Float16)acc[j];
    *(half4*)(Gout + (size_t)node * sOut + lane * 4) = o;
    if (Rout && lane == 0)
        Rout[node] = racc + sv * (Rin ? Rin[node] : 1.f);
}

// ---------------------------------------------------------------------------
// Weight-side precompute, consolidated into 4 launches.
// ---------------------------------------------------------------------------
__global__ __launch_bounds__(256) void wp1(
        const float* __restrict__ W2, const float* __restrict__ W3,
        const float* __restrict__ b2, const float* __restrict__ b3,
        float* __restrict__ W2sq, float* __restrict__ W3_2,
        float* __restrict__ bw2, float* __restrict__ bw3a) {
    int b = blockIdx.x, j = threadIdx.x;
    const float* A; const float* B; float* C;
    if (b < 256)      { A = W2 + b * 256;         B = W2; C = W2sq + b * 256; }
    else if (b < 512) { A = W3 + (b - 256) * 256; B = W3; C = W3_2 + (b - 256) * 256; }
    else if (b == 512){ A = b2;                   B = W2; C = bw2; }
    else              { A = b3;                   B = W3; C = bw3a; }
    float s = 0.f;
#pragma unroll 8
    for (int k = 0; k < 256; ++k) s += A[k] * B[k * 256 + j];
    C[j] = s;
}

__global__ __launch_bounds__(256) void wp2(
        const float* __restrict__ W3_2, const float* __restrict__ W3,
        const float* __restrict__ bw3a,
        float* __restrict__ W3_4, float* __restrict__ bw3b) {
    int b = blockIdx.x, j = threadIdx.x;
    const float* A; const float* B; float* C;
    if (b < 256) { A = W3_2 + b * 256; B = W3_2; C = W3_4 + b * 256; }
    else         { A = bw3a;           B = W3;   C = bw3b; }
    float s = 0.f;
#pragma unroll 8
    for (int k = 0; k < 256; ++k) s += A[k] * B[k * 256 + j];
    C[j] = s;
}

__global__ __launch_bounds__(256) void wp3(
        const float* __restrict__ W1, const float* __restrict__ W2sq,
        const float* __restrict__ W3_4, const float* __restrict__ Wp,
        const float* __restrict__ W3, const float* __restrict__ bw3b,
        _Float16* __restrict__ Mt, float* __restrict__ bw3c) {
    int b = blockIdx.x, j = threadIdx.x;
    if (b == 768) {   // bw3c = bw3b @ W3
        float s = 0.f;
#pragma unroll 8
        for (int k = 0; k < 256; ++k) s += bw3b[k] * W3[k * 256 + j];
        bw3c[j] = s;
        return;
    }
    int kk = b;                       // output row of Mcat = column of Mt
    int blk = kk >> 8;                // 0,1,2
    const float* A = (blk == 0) ? (W1 + kk * 256)
                   : (blk == 1) ? (W2sq + (kk - 256) * 256)
                                : (W3_4 + (kk - 512) * 256);
    const float* B = Wp + (size_t)(blk * 256) * 768;
    float s0 = 0.f, s1 = 0.f, s2 = 0.f;
#pragma unroll 4
    for (int m = 0; m < 256; ++m) {
        float a = A[m];
        const float* br = B + (size_t)m * 768;
        s0 += a * br[j]; s1 += a * br[j + 256]; s2 += a * br[j + 512];
    }
    // Mt[n][k] = Mcat[k][n]
    Mt[(size_t)j * 768 + kk]         = (_Float16)s0;
    Mt[(size_t)(j + 256) * 768 + kk] = (_Float16)s1;
    Mt[(size_t)(j + 512) * 768 + kk] = (_Float16)s2;
}

__global__ __launch_bounds__(256) void wp4(
        const float* __restrict__ Wp,
        const float* __restrict__ b1, const float* __restrict__ b2,
        const float* __restrict__ b3, const float* __restrict__ bp,
        const float* __restrict__ bw2, const float* __restrict__ bw3a,
        const float* __restrict__ bw3b, const float* __restrict__ bw3c,
        float* __restrict__ u1, float* __restrict__ u2,
        float* __restrict__ u3, float* __restrict__ c0) {
    int vec = blockIdx.x / 3, chunk = blockIdx.x % 3;
    int j = chunk * 256 + threadIdx.x;
    const float* P1 = Wp;
    const float* P2 = Wp + (size_t)256 * 768;
    const float* P3 = Wp + (size_t)512 * 768;
    float s = 0.f;
    if (vec == 0) {        // u1 = bw2@P2 + bw3a@P3
#pragma unroll 8
        for (int k = 0; k < 256; ++k) s += bw2[k] * P2[(size_t)k * 768 + j];
#pragma unroll 8
        for (int k = 0; k < 256; ++k) s += bw3a[k] * P3[(size_t)k * 768 + j];
        u1[j] = s;
    } else if (vec == 1) { // u2 = bw3b@P3
#pragma unroll 8
        for (int k = 0; k < 256; ++k) s += bw3b[k] * P3[(size_t)k * 768 + j];
        u2[j] = s;
    } else if (vec == 2) { // u3 = bw3c@P3
#pragma unroll 8
        for (int k = 0; k < 256; ++k) s += bw3c[k] * P3[(size_t)k * 768 + j];
        u3[j] = s;
    } else {               // c0 = b1@P1 + b2@P2 + b3@P3 + bp
#pragma unroll 8
        for (int k = 0; k < 256; ++k) s += b1[k] * P1[(size_t)k * 768 + j];
#pragma unroll 8
        for (int k = 0; k < 256; ++k) s += b2[k] * P2[(size_t)k * 768 + j];
#pragma unroll 8
        for (int k = 0; k < 256; ++k) s += b3[k] * P3[(size_t)k * 768 + j];
        c0[j] = s + bp[j];
    }
}

// ---------------------------------------------------------------------------
// MFMA GEMM: Ch[M,768](fp16) = A[M,768](fp16) @ B + rank-1 epilogue.
// 128x128 tile, 4 waves x (4x4 of mfma_f32_16x16x32_f16), BK=64, dbuf,
// counted-vmcnt pipeline (round 4).
// v6: VALU-cut. Round-4 counters: VALUBusy 30% > MfmaUtil 24.5% at 2
//     waves/SIMD -> staging address recompute (2x 64-bit mul-by-768 per
//     load, 8 loads/step) was co-critical with the MFMA pipe. Now: per-it
//     global pointers computed ONCE, incremented by 64 elems (128 B) per
//     K-step; ds_read byte offsets precomputed (loop-invariant).
//     Grid stays over NPAD rows (392x6 = 2352 % 8 == 0) for the bijective
//     XCD-chunked swizzle. Do not "optimize" back to 391.
// ---------------------------------------------------------------------------
__device__ inline void g2lds16(const void* g, void* l) {
    __builtin_amdgcn_global_load_lds(
        (__attribute__((address_space(1))) void*)g,
        (__attribute__((address_space(3))) void*)l, 16, 0, 0);
}

__global__ __launch_bounds__(256) void gemm_mfma(
        const _Float16* __restrict__ A,   // [NPAD][768]
        const _Float16* __restrict__ Bt,  // [768][768], Bt[n][k]
        _Float16* __restrict__ Ch, int M,
        const float* __restrict__ R1, const float* __restrict__ R2,
        const float* __restrict__ R3,
        const float* __restrict__ u1, const float* __restrict__ u2,
        const float* __restrict__ u3, const float* __restrict__ c0) {
    __shared__ _Float16 As[2][128 * 64];   // 32 KB
    __shared__ _Float16 Bs[2][128 * 64];   // 32 KB
    const int tid  = threadIdx.x;
    const int wid  = tid >> 6;
    const int lane = tid & 63;
    // XCD-chunked swizzle (bijective: 2352 % 8 == 0, 294 blocks per XCD).
    const int lid  = blockIdx.y * (DOUT / 128) + blockIdx.x;
    const int pair = (lid & 7) * (NPAD / 128 * (DOUT / 128) / 8) + (lid >> 3);
    const int bm = (pair / (DOUT / 128)) * 128;
    const int bn = (pair % (DOUT / 128)) * 128;
    const int wm = (wid >> 1) * 64;
    const int wn = (wid & 1) * 64;
    const int l15  = lane & 15;
    const int quad = lane >> 4;

    f32x4 acc[4][4] = {};

    // ---- staging pointers: computed once, += 64 elems per K-step ----
    const _Float16* pa[4];
    const _Float16* pb[4];
#pragma unroll
    for (int it = 0; it < 4; ++it) {
        int row = wid * 32 + it * 8 + (lane >> 3);      // 0..127
        int lc  = ((lane & 7) - row) & 7;               // logical chunk (swizzle)
        pa[it] = A  + (size_t)(bm + row) * DOUT + lc * 8;
        pb[it] = Bt + (size_t)(bn + row) * DOUT + lc * 8;
    }
    auto stage = [&](int buf) {
#pragma unroll
        for (int it = 0; it < 4; ++it) {
            g2lds16(pa[it], &As[buf][(size_t)(wid * 32 + it * 8) * 64]);
            g2lds16(pb[it], &Bs[buf][(size_t)(wid * 32 + it * 8) * 64]);
        }
#pragma unroll
        for (int it = 0; it < 4; ++it) { pa[it] += 64; pb[it] += 64; }
    };

    // ---- ds_read byte offsets: loop-invariant, precomputed ----
    int offA[8], offB[8];   // [h*4+i]
#pragma unroll
    for (int i = 0; i < 4; ++i) {
        int ra = wm + i * 16 + l15;
        int rb = wn + i * 16 + l15;
#pragma unroll
        for (int h = 0; h < 2; ++h) {
            offA[h * 4 + i] = ra * 64 + (((h * 4 + quad) + ra) & 7) * 8;
            offB[h * 4 + i] = rb * 64 + (((h * 4 + quad) + rb) & 7) * 8;
        }
    }

    const int NT = DOUT / 64;   // 12 K-steps
    stage(0);                   // 8 loads in flight for buf0
    int cur = 0;
    for (int t = 0; t < NT; ++t) {
        if (t + 1 < NT) {
            stage(cur ^ 1);     // +8 loads for nxt (stay in flight)
            __builtin_amdgcn_sched_barrier(0);
            asm volatile("s_waitcnt vmcnt(8)" ::: "memory");  // cur loads done
        } else {
            asm volatile("s_waitcnt vmcnt(0)" ::: "memory");  // last tile
        }
        __builtin_amdgcn_s_barrier();       // all waves' cur-writes visible
        __builtin_amdgcn_sched_barrier(0);
        half8 af[2][4], bf[2][4];
#pragma unroll
        for (int i = 0; i < 4; ++i) {
#pragma unroll
            for (int h = 0; h < 2; ++h) {
                af[h][i] = *(const half8*)(&As[cur][offA[h * 4 + i]]);
                bf[h][i] = *(const half8*)(&Bs[cur][offB[h * 4 + i]]);
            }
        }
#pragma unroll
        for (int mi = 0; mi < 4; ++mi)
#pragma unroll
            for (int ni = 0; ni < 4; ++ni) {
                acc[mi][ni] = __builtin_amdgcn_mfma_f32_16x16x32_f16(
                    af[0][mi], bf[0][ni], acc[mi][ni], 0, 0, 0);
                acc[mi][ni] = __builtin_amdgcn_mfma_f32_16x16x32_f16(
                    af[1][mi], bf[1][ni], acc[mi][ni], 0, 0, 0);
            }
        __builtin_amdgcn_sched_barrier(0);
        __builtin_amdgcn_s_barrier();       // all waves done READING cur
        cur ^= 1;
    }

    float e0[4], e1[4], e2[4], e3[4];
#pragma unroll
    for (int ni = 0; ni < 4; ++ni) {
        int gc = bn + wn + ni * 16 + l15;
        e0[ni] = c0[gc]; e1[ni] = u1[gc]; e2[ni] = u2[gc]; e3[ni] = u3[gc];
    }
#pragma unroll
    for (int mi = 0; mi < 4; ++mi) {
#pragma unroll
        for (int r = 0; r < 4; ++r) {
            int gr = bm + wm + mi * 16 + quad * 4 + r;
            if (gr >= M) continue;
            float r1 = R1[gr], r2 = R2[gr], r3 = R3[gr];
#pragma unroll
            for (int ni = 0; ni < 4; ++ni) {
                int gc = bn + wn + ni * 16 + l15;
                Ch[(size_t)gr * DOUT + gc] = (_Float16)(
                    acc[mi][ni][r] + e0[ni] + r1 * e1[ni] + r2 * e2[ni] + r3 * e3[ni]);
            }
        }
    }
}

// ---------------------------------------------------------------------------
// Fused LayerNorm + exact GELU: fp16 in (Ch), fp32 out. One WAVE per row.
// ---------------------------------------------------------------------------
__global__ __launch_bounds__(256) void ln_gelu_kernel(
        const _Float16* __restrict__ Ch, float* __restrict__ out,
        const float* __restrict__ gamma, const float* __restrict__ beta) {
    int row = blockIdx.x * 4 + (threadIdx.x >> 6);
    if (row >= NN) return;
    int lane = threadIdx.x & 63;
    const _Float16* p = Ch + (size_t)row * DOUT;
    half4 h0 = *(const half4*)(p + lane * 4);
    half4 h1 = *(const half4*)(p + 256 + lane * 4);
    half4 h2 = *(const half4*)(p + 512 + lane * 4);
    float v[12];
#pragma unroll
    for (int j = 0; j < 4; ++j) {
        v[j]     = (float)h0[j];
        v[4 + j] = (float)h1[j];
        v[8 + j] = (float)h2[j];
    }
    float s = 0.f, s2 = 0.f;
#pragma unroll
    for (int j = 0; j < 12; ++j) { s += v[j]; s2 += v[j] * v[j]; }
#pragma unroll
    for (int m = 1; m < 64; m <<= 1) {
        s += __shfl_xor(s, m);
        s2 += __shfl_xor(s2, m);
    }
    float mu = s * (1.f / 768.f);
    float var = s2 * (1.f / 768.f) - mu * mu;
    float inv = rsqrtf(var + 1e-5f);
    const float kk = 0.70710678118654752f;
    float* po = out + (size_t)row * DOUT;
#pragma unroll
    for (int i = 0; i < 3; ++i) {
        int c = i * 256 + lane * 4;
        float4 g = *(const float4*)(gamma + c);
        float4 b = *(const float4*)(beta + c);
        float4 o;
        float y0 = (v[i * 4 + 0] - mu) * inv * g.x + b.x;
        float y1 = (v[i * 4 + 1] - mu) * inv * g.y + b.y;
        float y2 = (v[i * 4 + 2] - mu) * inv * g.z + b.z;
        float y3 = (v[i * 4 + 3] - mu) * inv * g.w + b.w;
        o.x = 0.5f * y0 * (1.f + erff(y0 * kk));
        o.y = 0.5f * y1 * (1.f + erff(y1 * kk));
        o.z = 0.5f * y2 * (1.f + erff(y2 * kk));
        o.w = 0.5f * y3 * (1.f + erff(y3 * kk));
        *(float4*)(po + c) = o;
    }
}

// ---------------------------------------------------------------------------
// Launch
// ---------------------------------------------------------------------------
extern "C" void kernel_launch(void* const* d_in, const int* in_sizes, int n_in,
                              void* d_out, int out_size, void* d_ws, size_t ws_size,
                              hipStream_t stream) {
    const float* x     = (const float*)d_in[0];
    const int*   ei    = (const int*)d_in[1];
    const float* ea    = (const float*)d_in[2];
    const float* W1    = (const float*)d_in[3];
    const float* b1    = (const float*)d_in[4];
    const float* W2    = (const float*)d_in[5];
    const float* b2    = (const float*)d_in[6];
    const float* W3    = (const float*)d_in[7];
    const float* b3    = (const float*)d_in[8];
    const float* Wp    = (const float*)d_in[9];
    const float* bp    = (const float*)d_in[10];
    const float* gamma = (const float*)d_in[11];
    const float* beta  = (const float*)d_in[12];
    float* out = (float*)d_out;

    char* w = (char*)d_ws;
    auto alloc = [&](size_t bytes) -> void* {
        void* p = (void*)w;
        w += (bytes + 255) & ~(size_t)255;
        return p;
    };
    _Float16* Acat = (_Float16*)alloc((size_t)NPAD * DOUT * 2);  // 77 MB  G1|G2|G4
    _Float16* Xh   = (_Float16*)alloc((size_t)NN * DIN * 2);     // 25 MB
    _Float16* G3h  = (_Float16*)alloc((size_t)NN * DIN * 2);     // 25 MB
    _Float16* Ch   = (_Float16*)alloc((size_t)NN * DOUT * 2);    // 77 MB
    _Float16* Mt   = (_Float16*)alloc((size_t)DOUT * DOUT * 2);  // 1.2 MB
    int*   col    = (int*)alloc((size_t)NE * 4);
    float* val    = (float*)alloc((size_t)NE * 4);
    float* deg    = (float*)alloc((size_t)NN * 4);
    float* dinv   = (float*)alloc((size_t)NN * 4);
    int*   cnt    = (int*)alloc((size_t)NN * 4);
    int*   rowp   = (int*)alloc((size_t)(NN + 1) * 4);
    int*   cursor = (int*)alloc((size_t)NN * 4);
    int*   bsum   = (int*)alloc((size_t)NBS * 4);
    int*   boff   = (int*)alloc((size_t)NBS * 4);
    float* R1     = (float*)alloc((size_t)NN * 4);
    float* R2     = (float*)alloc((size_t)NN * 4);
    float* R3     = (float*)alloc((size_t)NN * 4);
    float* W2sq   = (float*)alloc(256 * 256 * 4);
    float* W3_2   = (float*)alloc(256 * 256 * 4);
    float* W3_4   = (float*)alloc(256 * 256 * 4);
    float* bw2    = (float*)alloc(256 * 4);
    float* bw3a   = (float*)alloc(256 * 4);
    float* bw3b   = (float*)alloc(256 * 4);
    float* bw3c   = (float*)alloc(256 * 4);
    float* u1     = (float*)alloc(768 * 4);
    float* u2     = (float*)alloc(768 * 4);
    float* u3     = (float*)alloc(768 * 4);
    float* c0     = (float*)alloc(768 * 4);

    const int nb_n = (NN + 255) / 256;
    const int nb_e = (NE + 255) / 256;

    // degree + CSR (hierarchical scan)
    init_deg_cnt<<<nb_n, 256, 0, stream>>>(deg, cnt);
    edge_deg_cnt<<<nb_e, 256, 0, stream>>>(ei, ea, deg, cnt);
    compute_dinv<<<nb_n, 256, 0, stream>>>(deg, dinv);
    scan_bsum<<<NBS, 256, 0, stream>>>(cnt, bsum);
    scan_boff<<<1, 256, 0, stream>>>(bsum, boff);
    scan_write<<<NBS, 256, 0, stream>>>(cnt, boff, rowp, cursor);
    edge_scatter<<<nb_e, 256, 0, stream>>>(ei, ea, dinv, cursor, col, val);

    // x -> fp16
    x2h_kernel<<<(NN * DIN / 4 + 255) / 256, 256, 0, stream>>>(x, Xh);

    // weight-side precompute, 4 launches
    wp1<<<514, 256, 0, stream>>>(W2, W3, b2, b3, W2sq, W3_2, bw2, bw3a);
    wp2<<<257, 256, 0, stream>>>(W3_2, W3, bw3a, W3_4, bw3b);
    wp3<<<769, 256, 0, stream>>>(W1, W2sq, W3_4, Wp, W3, bw3b, Mt, bw3c);
    wp4<<<12, 256, 0, stream>>>(Wp, b1, b2, b3, bp, bw2, bw3a, bw3b, bw3c,
                                u1, u2, u3, c0);

    // shared aggregation chain: G1=Ax, G2=A G1, G3=A G2, G4=A G3 (+ R chain)
    const int nb_a = (NN + 3) / 4;
    agg_kernel<<<nb_a, 256, 0, stream>>>(Xh, DIN,          Acat + 0,   DOUT, nullptr, R1, rowp, col, val, dinv);
    agg_kernel<<<nb_a, 256, 0, stream>>>(Acat + 0,   DOUT, Acat + 256, DOUT, R1,      R2, rowp, col, val, dinv);
    agg_kernel<<<nb_a, 256, 0, stream>>>(Acat + 256, DOUT, G3h,        DIN,  R2,      R3, rowp, col, val, dinv);
    agg_kernel<<<nb_a, 256, 0, stream>>>(G3h,        DIN,  Acat + 512, DOUT, nullptr, nullptr, rowp, col, val, dinv);

    // fused projection GEMM (fp16 MFMA) + bias epilogue, fp16 output
    // NOTE: grid covers NPAD rows (392), NOT ceil(NN/128)=391 — required for
    // the bijective XCD swizzle (2352 % 8 == 0). Do not "optimize" back.
    dim3 grid(DOUT / 128, NPAD / 128);
    gemm_mfma<<<grid, 256, 0, stream>>>(Acat, Mt, Ch, NN, R1, R2, R3, u1, u2, u3, c0);

    // LayerNorm + exact GELU: fp16 in, fp32 out, wave-per-row
    ln_gelu_kernel<<<(NN + 3) / 4, 256, 0, stream>>>(Ch, out, gamma, beta);
}